// Round 2
// baseline (1430.268 us; speedup 1.0000x reference)
//
#include <hip/hip_runtime.h>

#define BDIM 4
#define SEQ 1024
#define CH 256
#define DMODEL 512
#define DINNER 512
#define DSTATE 16
#define DTRANK 32
#define NROWS (BDIM * SEQ)   // 4096

__device__ __forceinline__ float nan2num(float x) {
    if (isnan(x)) return 0.f;
    if (isinf(x)) return x > 0.f ? 1.f : -1.f;
    return x;
}

__device__ __forceinline__ float silu_f(float x) { return x / (1.f + __expf(-x)); }
__device__ __forceinline__ float sigmoid_f(float x) { return 1.f / (1.f + __expf(-x)); }
__device__ __forceinline__ float softplus_f(float x) {
    return x > 20.f ? x : log1pf(__expf(x));
}

// ---------------------------------------------------------------------------
// Kernel 1: nan_to_num + LN(i0), LN(i1) -> x0n (B*N,256) and combined (B*N,512)
// ---------------------------------------------------------------------------
__global__ void ln01_kernel(const float* __restrict__ i0, const float* __restrict__ i1,
                            const float* __restrict__ g0, const float* __restrict__ b0,
                            const float* __restrict__ g1, const float* __restrict__ b1,
                            float* __restrict__ x0n, float* __restrict__ combined) {
    int row = blockIdx.x;
    int t = threadIdx.x;
    __shared__ float s1[256], s2[256];

    // --- LN of input0 ---
    float v0 = nan2num(i0[row * CH + t]);
    s1[t] = v0; s2[t] = v0 * v0;
    __syncthreads();
    for (int s = 128; s > 0; s >>= 1) {
        if (t < s) { s1[t] += s1[t + s]; s2[t] += s2[t + s]; }
        __syncthreads();
    }
    float m = s1[0] / (float)CH;
    float var = s2[0] / (float)CH - m * m;
    float r = rsqrtf(var + 1e-5f);
    float o0 = (v0 - m) * r * g0[t] + b0[t];
    x0n[row * CH + t] = o0;
    combined[row * DMODEL + t] = o0;
    __syncthreads();

    // --- LN of input1 ---
    float v1 = nan2num(i1[row * CH + t]);
    s1[t] = v1; s2[t] = v1 * v1;
    __syncthreads();
    for (int s = 128; s > 0; s >>= 1) {
        if (t < s) { s1[t] += s1[t + s]; s2[t] += s2[t + s]; }
        __syncthreads();
    }
    m = s1[0] / (float)CH;
    var = s2[0] / (float)CH - m * m;
    r = rsqrtf(var + 1e-5f);
    float o1 = (v1 - m) * r * g1[t] + b1[t];
    combined[row * DMODEL + CH + t] = o1;
}

// ---------------------------------------------------------------------------
// Generic fp32 GEMM (NT): C[m,n] = sum_k A[m,k]*W[n,k] (+bias[n]) (+softplus)
// A fp32 row-major (lda), W fp32 row-major (ldw), C fp32 row-major (ldc)
// M % 64 == 0, N % 64 == 0, K % 16 == 0 (all shapes here satisfy this)
// ---------------------------------------------------------------------------
__global__ void gemm_nt_kernel(const float* __restrict__ A, int lda,
                               const float* __restrict__ W, int ldw,
                               float* __restrict__ C, int ldc,
                               int K, const float* __restrict__ bias, int act) {
    __shared__ float As[16][65];
    __shared__ float Ws[16][65];
    const int t = threadIdx.x;
    const int m0 = blockIdx.y * 64;
    const int n0 = blockIdx.x * 64;

    float acc[4][4] = {};
    const int ms = (t >> 4) * 4;
    const int ns = (t & 15) * 4;

    for (int k0 = 0; k0 < K; k0 += 16) {
#pragma unroll
        for (int i = 0; i < 4; ++i) {
            int e = t + i * 256;
            int rr = e >> 4;      // 0..63
            int cc = e & 15;      // 0..15
            As[cc][rr] = A[(m0 + rr) * lda + k0 + cc];
            Ws[cc][rr] = W[(n0 + rr) * ldw + k0 + cc];
        }
        __syncthreads();
#pragma unroll
        for (int k = 0; k < 16; ++k) {
            float a[4], b[4];
#pragma unroll
            for (int j = 0; j < 4; ++j) { a[j] = As[k][ms + j]; b[j] = Ws[k][ns + j]; }
#pragma unroll
            for (int i = 0; i < 4; ++i)
#pragma unroll
                for (int j = 0; j < 4; ++j) acc[i][j] += a[i] * b[j];
        }
        __syncthreads();
    }

#pragma unroll
    for (int i = 0; i < 4; ++i) {
        int m = m0 + ms + i;
#pragma unroll
        for (int j = 0; j < 4; ++j) {
            int n = n0 + ns + j;
            float c = acc[i][j];
            if (bias) c += bias[n];
            if (act == 1) c = softplus_f(c);
            C[m * ldc + n] = c;
        }
    }
}

// ---------------------------------------------------------------------------
// Kernel: weight = clip(sigmoid(LN(cw_pre)), 0.01, 0.99), in place (row len 256)
// ---------------------------------------------------------------------------
__global__ void weight_ln_kernel(float* __restrict__ wbuf,
                                 const float* __restrict__ g, const float* __restrict__ b) {
    int row = blockIdx.x;
    int t = threadIdx.x;
    __shared__ float s1[256], s2[256];
    float v = wbuf[row * CH + t];
    s1[t] = v; s2[t] = v * v;
    __syncthreads();
    for (int s = 128; s > 0; s >>= 1) {
        if (t < s) { s1[t] += s1[t + s]; s2[t] += s2[t + s]; }
        __syncthreads();
    }
    float m = s1[0] / (float)CH;
    float var = s2[0] / (float)CH - m * m;
    float r = rsqrtf(var + 1e-5f);
    float o = sigmoid_f((v - m) * r * g[t] + b[t]);
    o = fminf(fmaxf(o, 0.01f), 0.99f);
    wbuf[row * CH + t] = o;
}

// ---------------------------------------------------------------------------
// Kernel: depthwise causal conv (width 4) + bias + silu.
// xz layout (row=b*N+l, e) with e in [0,1024); x part is e in [0,512).
// rev=1: operate on the l-reversed sequence (for the backward direction).
// out layout: (row, d) with row indexing the (possibly reversed) sequence pos.
// ---------------------------------------------------------------------------
__global__ void conv_silu_kernel(const float* __restrict__ xz,
                                 const float* __restrict__ w, const float* __restrict__ wb,
                                 float* __restrict__ out, int rev) {
    int flat = blockIdx.x * 256 + threadIdx.x;   // over 4096*512
    int d = flat & (DINNER - 1);
    int row = flat >> 9;
    int l = row & (SEQ - 1);
    int b = row >> 10;
    float acc = wb[d];
#pragma unroll
    for (int k = 0; k < 4; ++k) {
        int j = l - 3 + k;
        if (j >= 0) {
            int lp = rev ? (SEQ - 1 - j) : j;
            acc += xz[(b * SEQ + lp) * (2 * DINNER) + d] * w[d * 4 + k];
        }
    }
    out[flat] = silu_f(acc);
}

// ---------------------------------------------------------------------------
// Selective scan. One thread per (d-group lane n, d). Block = 256 = 16 d x 16 n.
// grid = (DINNER/16, B). delta/u layout (row,512); xdbl layout (row,64).
// rev=1: sequence is reversed; write output flipped back to natural order.
// ---------------------------------------------------------------------------
__global__ void scan_kernel(const float* __restrict__ delta, const float* __restrict__ u,
                            const float* __restrict__ xdbl,
                            const float* __restrict__ A_log, const float* __restrict__ Dv,
                            float* __restrict__ yout, int rev) {
    int t = threadIdx.x;
    int n = t & 15;
    int dg = t >> 4;
    int d = blockIdx.x * 16 + dg;
    int b = blockIdx.y;
    float a = -__expf(A_log[d * DSTATE + n]);
    float Dd = Dv[d];
    float h = 0.f;
    int base = b * SEQ;
    for (int l = 0; l < SEQ; ++l) {
        int row = base + l;
        float dl = delta[row * DINNER + d];
        float ul = u[row * DINNER + d];
        float Bn = xdbl[row * 64 + DTRANK + n];
        float Cn = xdbl[row * 64 + DTRANK + DSTATE + n];
        h = __expf(dl * a) * h + (dl * ul) * Bn;
        float yp = h * Cn;
        yp += __shfl_xor(yp, 8, 16);
        yp += __shfl_xor(yp, 4, 16);
        yp += __shfl_xor(yp, 2, 16);
        yp += __shfl_xor(yp, 1, 16);
        if (n == 0) {
            int orow = rev ? (base + SEQ - 1 - l) : row;
            yout[orow * DINNER + d] = yp + Dd * ul;
        }
    }
}

// ---------------------------------------------------------------------------
// Kernel: y = 0.5*(y_f + y_b)*silu(z), then LN over 512 (mnorm) -> yn
// ---------------------------------------------------------------------------
__global__ void combine_mnorm_kernel(const float* __restrict__ yf, const float* __restrict__ yb,
                                     const float* __restrict__ xz,
                                     const float* __restrict__ g, const float* __restrict__ b,
                                     float* __restrict__ yn) {
    int row = blockIdx.x;
    int t = threadIdx.x;
    __shared__ float s1[256], s2[256];
    int j0 = t, j1 = t + 256;
    float z0 = xz[row * (2 * DINNER) + DINNER + j0];
    float z1 = xz[row * (2 * DINNER) + DINNER + j1];
    float va = 0.5f * (yf[row * DINNER + j0] + yb[row * DINNER + j0]) * silu_f(z0);
    float vb = 0.5f * (yf[row * DINNER + j1] + yb[row * DINNER + j1]) * silu_f(z1);
    s1[t] = va + vb; s2[t] = va * va + vb * vb;
    __syncthreads();
    for (int s = 128; s > 0; s >>= 1) {
        if (t < s) { s1[t] += s1[t + s]; s2[t] += s2[t + s]; }
        __syncthreads();
    }
    float m = s1[0] / (float)DINNER;
    float var = s2[0] / (float)DINNER - m * m;
    float r = rsqrtf(var + 1e-5f);
    yn[row * DINNER + j0] = (va - m) * r * g[j0] + b[j0];
    yn[row * DINNER + j1] = (vb - m) * r * g[j1] + b[j1];
}

// ---------------------------------------------------------------------------
// Kernel: plain LN over 512 (pnorm): out = LN(in)
// ---------------------------------------------------------------------------
__global__ void ln512_kernel(const float* __restrict__ in,
                             const float* __restrict__ g, const float* __restrict__ b,
                             float* __restrict__ out) {
    int row = blockIdx.x;
    int t = threadIdx.x;
    __shared__ float s1[256], s2[256];
    int j0 = t, j1 = t + 256;
    float va = in[row * DMODEL + j0];
    float vb = in[row * DMODEL + j1];
    s1[t] = va + vb; s2[t] = va * va + vb * vb;
    __syncthreads();
    for (int s = 128; s > 0; s >>= 1) {
        if (t < s) { s1[t] += s1[t + s]; s2[t] += s2[t + s]; }
        __syncthreads();
    }
    float m = s1[0] / (float)DMODEL;
    float var = s2[0] / (float)DMODEL - m * m;
    float r = rsqrtf(var + 1e-5f);
    out[row * DMODEL + j0] = (va - m) * r * g[j0] + b[j0];
    out[row * DMODEL + j1] = (vb - m) * r * g[j1] + b[j1];
}

// ---------------------------------------------------------------------------
// Final: out = nan_to_num(o2)*w + x0n*(1-w) + nan_to_num(i0)  -> fp32
// ---------------------------------------------------------------------------
__global__ void final_kernel(const float* __restrict__ o2, const float* __restrict__ weight,
                             const float* __restrict__ x0n, const float* __restrict__ i0,
                             float* __restrict__ out) {
    int idx = blockIdx.x * 256 + threadIdx.x;
    float o = nan2num(o2[idx]);
    float w = weight[idx];
    float x0 = x0n[idx];
    float skip = nan2num(i0[idx]);
    out[idx] = o * w + x0 * (1.f - w) + skip;
}

extern "C" void kernel_launch(void* const* d_in, const int* in_sizes, int n_in,
                              void* d_out, int out_size, void* d_ws, size_t ws_size,
                              hipStream_t stream) {
    (void)in_sizes; (void)n_in; (void)out_size; (void)ws_size;
    // setup_inputs() dict order (all float32 per the reference):
    const float* input0    = (const float*)d_in[0];
    const float* input1    = (const float*)d_in[1];
    const float* norm0_g   = (const float*)d_in[2];
    const float* norm0_b   = (const float*)d_in[3];
    const float* norm1_g   = (const float*)d_in[4];
    const float* norm1_b   = (const float*)d_in[5];
    const float* in_proj_w = (const float*)d_in[6];
    const float* convf_w   = (const float*)d_in[7];
    const float* convf_b   = (const float*)d_in[8];
    const float* xprojf_w  = (const float*)d_in[9];
    const float* dtf_w     = (const float*)d_in[10];
    const float* dtf_b     = (const float*)d_in[11];
    const float* A_log_f   = (const float*)d_in[12];
    const float* D_f       = (const float*)d_in[13];
    const float* convb_w   = (const float*)d_in[14];
    const float* convb_b   = (const float*)d_in[15];
    const float* xprojb_w  = (const float*)d_in[16];
    const float* dtb_w     = (const float*)d_in[17];
    const float* dtb_b     = (const float*)d_in[18];
    const float* A_log_b   = (const float*)d_in[19];
    const float* D_b       = (const float*)d_in[20];
    const float* mnorm_g   = (const float*)d_in[21];
    const float* mnorm_b   = (const float*)d_in[22];
    const float* outproj_w = (const float*)d_in[23];
    const float* pnorm_g   = (const float*)d_in[24];
    const float* pnorm_b   = (const float*)d_in[25];
    const float* projback_w= (const float*)d_in[26];
    const float* projback_b= (const float*)d_in[27];
    const float* cw_w      = (const float*)d_in[28];
    const float* cw_b      = (const float*)d_in[29];
    const float* cwln_g    = (const float*)d_in[30];
    const float* cwln_b    = (const float*)d_in[31];

    // workspace layout (floats), ~86 MB total
    float* ws = (float*)d_ws;
    float* x0n      = ws;                       // 1,048,576
    float* combined = x0n + 1048576;            // 2,097,152
    float* xz       = combined + 2097152;       // 4,194,304
    float* weight   = xz + 4194304;             // 1,048,576 (cw_pre computed in place)
    float* xdbl_f   = weight + 1048576;         //   262,144
    float* xdbl_b   = xdbl_f + 262144;          //   262,144
    float* xconv_f  = xdbl_b + 262144;          // 2,097,152
    float* xconv_b  = xconv_f + 2097152;        // 2,097,152
    float* delta_f  = xconv_b + 2097152;        // 2,097,152
    float* delta_b  = delta_f + 2097152;        // 2,097,152
    float* y_f      = delta_b + 2097152;        // 2,097,152
    float* y_b      = y_f + 2097152;            // 2,097,152
    // reuse dead buffers:
    float* yn  = combined;   // dead after GEMMs 1&2
    float* o1  = xconv_f;    // dead after scan
    float* on1 = xconv_b;    // dead after scan
    float* o2  = delta_f;    // dead after scan

    // 1. LN of both inputs -> x0n, combined
    ln01_kernel<<<NROWS, 256, 0, stream>>>(input0, input1, norm0_g, norm0_b,
                                           norm1_g, norm1_b, x0n, combined);

    // 2. xz = combined @ in_proj_w^T   (4096x512) x (1024x512)^T -> (4096,1024)
    gemm_nt_kernel<<<dim3(1024 / 64, NROWS / 64), 256, 0, stream>>>(
        combined, DMODEL, in_proj_w, DMODEL, xz, 2 * DINNER, DMODEL, nullptr, 0);

    // 3. cw_pre = combined @ cw_w^T + cw_b -> weight buffer (4096,256)
    gemm_nt_kernel<<<dim3(256 / 64, NROWS / 64), 256, 0, stream>>>(
        combined, DMODEL, cw_w, DMODEL, weight, CH, DMODEL, cw_b, 0);

    // 4. weight = clip(sigmoid(LN(cw_pre)))
    weight_ln_kernel<<<NROWS, 256, 0, stream>>>(weight, cwln_g, cwln_b);

    // 5. conv + silu for both directions
    conv_silu_kernel<<<NROWS * DINNER / 256, 256, 0, stream>>>(xz, convf_w, convf_b, xconv_f, 0);
    conv_silu_kernel<<<NROWS * DINNER / 256, 256, 0, stream>>>(xz, convb_w, convb_b, xconv_b, 1);

    // 6. x_dbl = xconv @ xproj_w^T  (4096,512)x(64,512)^T -> (4096,64)
    gemm_nt_kernel<<<dim3(1, NROWS / 64), 256, 0, stream>>>(
        xconv_f, DINNER, xprojf_w, DINNER, xdbl_f, 64, DINNER, nullptr, 0);
    gemm_nt_kernel<<<dim3(1, NROWS / 64), 256, 0, stream>>>(
        xconv_b, DINNER, xprojb_w, DINNER, xdbl_b, 64, DINNER, nullptr, 0);

    // 7. delta = softplus(x_dbl[:, :32] @ dt_w^T + dt_b)  (4096,512)
    gemm_nt_kernel<<<dim3(512 / 64, NROWS / 64), 256, 0, stream>>>(
        xdbl_f, 64, dtf_w, DTRANK, delta_f, DINNER, DTRANK, dtf_b, 1);
    gemm_nt_kernel<<<dim3(512 / 64, NROWS / 64), 256, 0, stream>>>(
        xdbl_b, 64, dtb_w, DTRANK, delta_b, DINNER, DTRANK, dtb_b, 1);

    // 8. selective scan, both directions (backward writes flipped output)
    scan_kernel<<<dim3(DINNER / 16, BDIM), 256, 0, stream>>>(
        delta_f, xconv_f, xdbl_f, A_log_f, D_f, y_f, 0);
    scan_kernel<<<dim3(DINNER / 16, BDIM), 256, 0, stream>>>(
        delta_b, xconv_b, xdbl_b, A_log_b, D_b, y_b, 1);

    // 9. combine + mnorm LN -> yn
    combine_mnorm_kernel<<<NROWS, 256, 0, stream>>>(y_f, y_b, xz, mnorm_g, mnorm_b, yn);

    // 10. o1 = yn @ outproj_w^T  (4096,512)
    gemm_nt_kernel<<<dim3(512 / 64, NROWS / 64), 256, 0, stream>>>(
        yn, DINNER, outproj_w, DINNER, o1, DMODEL, DINNER, nullptr, 0);

    // 11. pnorm LN -> on1
    ln512_kernel<<<NROWS, 256, 0, stream>>>(o1, pnorm_g, pnorm_b, on1);

    // 12. o2 = on1 @ projback_w^T + projback_b  (4096,256)
    gemm_nt_kernel<<<dim3(256 / 64, NROWS / 64), 256, 0, stream>>>(
        on1, DMODEL, projback_w, DMODEL, o2, CH, DMODEL, projback_b, 0);

    // 13. final blend + skip -> fp32 out
    final_kernel<<<NROWS, 256, 0, stream>>>(o2, weight, x0n, input0, (float*)d_out);
}

// Round 3
// 535.146 us; speedup vs baseline: 2.6727x; 2.6727x over previous
//
#include <hip/hip_runtime.h>

#define BDIM 4
#define SEQ 1024
#define CH 256
#define DMODEL 512
#define DINNER 512
#define DSTATE 16
#define DTRANK 32
#define NROWS (BDIM * SEQ)   // 4096
#define NCHUNK 16
#define CHUNK (SEQ / NCHUNK) // 64

__device__ __forceinline__ float nan2num(float x) {
    if (isnan(x)) return 0.f;
    if (isinf(x)) return x > 0.f ? 1.f : -1.f;
    return x;
}

__device__ __forceinline__ float silu_f(float x) { return x / (1.f + __expf(-x)); }
__device__ __forceinline__ float sigmoid_f(float x) { return 1.f / (1.f + __expf(-x)); }
__device__ __forceinline__ float softplus_f(float x) {
    return x > 20.f ? x : log1pf(__expf(x));
}

// ---------------------------------------------------------------------------
// Kernel 1: nan_to_num + LN(i0), LN(i1) -> x0n (B*N,256) and combined (B*N,512)
// ---------------------------------------------------------------------------
__global__ void ln01_kernel(const float* __restrict__ i0, const float* __restrict__ i1,
                            const float* __restrict__ g0, const float* __restrict__ b0,
                            const float* __restrict__ g1, const float* __restrict__ b1,
                            float* __restrict__ x0n, float* __restrict__ combined) {
    int row = blockIdx.x;
    int t = threadIdx.x;
    __shared__ float s1[256], s2[256];

    float v0 = nan2num(i0[row * CH + t]);
    s1[t] = v0; s2[t] = v0 * v0;
    __syncthreads();
    for (int s = 128; s > 0; s >>= 1) {
        if (t < s) { s1[t] += s1[t + s]; s2[t] += s2[t + s]; }
        __syncthreads();
    }
    float m = s1[0] / (float)CH;
    float var = s2[0] / (float)CH - m * m;
    float r = rsqrtf(var + 1e-5f);
    float o0 = (v0 - m) * r * g0[t] + b0[t];
    x0n[row * CH + t] = o0;
    combined[row * DMODEL + t] = o0;
    __syncthreads();

    float v1 = nan2num(i1[row * CH + t]);
    s1[t] = v1; s2[t] = v1 * v1;
    __syncthreads();
    for (int s = 128; s > 0; s >>= 1) {
        if (t < s) { s1[t] += s1[t + s]; s2[t] += s2[t + s]; }
        __syncthreads();
    }
    m = s1[0] / (float)CH;
    var = s2[0] / (float)CH - m * m;
    r = rsqrtf(var + 1e-5f);
    float o1 = (v1 - m) * r * g1[t] + b1[t];
    combined[row * DMODEL + CH + t] = o1;
}

// ---------------------------------------------------------------------------
// Generic fp32 GEMM (NT): C[m,n] = sum_k A[m,k]*W[n,k] (+bias[n]) (+softplus)
// LDS stride 68 (17 float4) -> 16B aligned fragments, ds_read_b128 path.
// ---------------------------------------------------------------------------
__global__ void gemm_nt_kernel(const float* __restrict__ A, int lda,
                               const float* __restrict__ W, int ldw,
                               float* __restrict__ C, int ldc,
                               int K, const float* __restrict__ bias, int act) {
    __shared__ __align__(16) float As[16][68];
    __shared__ __align__(16) float Ws[16][68];
    const int t = threadIdx.x;
    const int m0 = blockIdx.y * 64;
    const int n0 = blockIdx.x * 64;

    float acc[4][4] = {};
    const int ms = (t >> 4) * 4;
    const int ns = (t & 15) * 4;

    for (int k0 = 0; k0 < K; k0 += 16) {
#pragma unroll
        for (int i = 0; i < 4; ++i) {
            int e = t + i * 256;
            int rr = e >> 4;      // 0..63
            int cc = e & 15;      // 0..15
            As[cc][rr] = A[(m0 + rr) * lda + k0 + cc];
            Ws[cc][rr] = W[(n0 + rr) * ldw + k0 + cc];
        }
        __syncthreads();
#pragma unroll
        for (int k = 0; k < 16; ++k) {
            float4 av = *(const float4*)&As[k][ms];
            float4 bv = *(const float4*)&Ws[k][ns];
            float a[4] = {av.x, av.y, av.z, av.w};
            float b[4] = {bv.x, bv.y, bv.z, bv.w};
#pragma unroll
            for (int i = 0; i < 4; ++i)
#pragma unroll
                for (int j = 0; j < 4; ++j) acc[i][j] += a[i] * b[j];
        }
        __syncthreads();
    }

#pragma unroll
    for (int i = 0; i < 4; ++i) {
        int m = m0 + ms + i;
#pragma unroll
        for (int j = 0; j < 4; ++j) {
            int n = n0 + ns + j;
            float c = acc[i][j];
            if (bias) c += bias[n];
            if (act == 1) c = softplus_f(c);
            C[m * ldc + n] = c;
        }
    }
}

// ---------------------------------------------------------------------------
// weight = clip(sigmoid(LN(cw_pre)), 0.01, 0.99), in place (row len 256)
// ---------------------------------------------------------------------------
__global__ void weight_ln_kernel(float* __restrict__ wbuf,
                                 const float* __restrict__ g, const float* __restrict__ b) {
    int row = blockIdx.x;
    int t = threadIdx.x;
    __shared__ float s1[256], s2[256];
    float v = wbuf[row * CH + t];
    s1[t] = v; s2[t] = v * v;
    __syncthreads();
    for (int s = 128; s > 0; s >>= 1) {
        if (t < s) { s1[t] += s1[t + s]; s2[t] += s2[t + s]; }
        __syncthreads();
    }
    float m = s1[0] / (float)CH;
    float var = s2[0] / (float)CH - m * m;
    float r = rsqrtf(var + 1e-5f);
    float o = sigmoid_f((v - m) * r * g[t] + b[t]);
    o = fminf(fmaxf(o, 0.01f), 0.99f);
    wbuf[row * CH + t] = o;
}

// ---------------------------------------------------------------------------
// depthwise causal conv (width 4) + bias + silu
// ---------------------------------------------------------------------------
__global__ void conv_silu_kernel(const float* __restrict__ xz,
                                 const float* __restrict__ w, const float* __restrict__ wb,
                                 float* __restrict__ out, int rev) {
    int flat = blockIdx.x * 256 + threadIdx.x;   // over 4096*512
    int d = flat & (DINNER - 1);
    int row = flat >> 9;
    int l = row & (SEQ - 1);
    int b = row >> 10;
    float acc = wb[d];
#pragma unroll
    for (int k = 0; k < 4; ++k) {
        int j = l - 3 + k;
        if (j >= 0) {
            int lp = rev ? (SEQ - 1 - j) : j;
            acc += xz[(b * SEQ + lp) * (2 * DINNER) + d] * w[d * 4 + k];
        }
    }
    out[flat] = silu_f(acc);
}

// ---------------------------------------------------------------------------
// Chunked selective scan, pass 1: per-chunk (prodA, partial h).
// block = 256 = 16 d x 16 n ; grid = (DINNER/16, NCHUNK, B)
// ---------------------------------------------------------------------------
__global__ void scan_pass1_kernel(const float* __restrict__ delta, const float* __restrict__ u,
                                  const float* __restrict__ xdbl,
                                  const float* __restrict__ A_log,
                                  float* __restrict__ chunkA, float* __restrict__ chunkH) {
    int t = threadIdx.x;
    int n = t & 15;
    int dg = t >> 4;
    int d = blockIdx.x * 16 + dg;
    int c = blockIdx.y;
    int b = blockIdx.z;
    float a = -__expf(A_log[d * DSTATE + n]);
    float P = 1.f, hp = 0.f;
    int base = b * SEQ + c * CHUNK;
    for (int s = 0; s < CHUNK; ++s) {
        int row = base + s;
        float dl = delta[row * DINNER + d];
        float ul = u[row * DINNER + d];
        float Bn = xdbl[row * 64 + DTRANK + n];
        float dA = __expf(dl * a);
        hp = dA * hp + dl * ul * Bn;
        P *= dA;
    }
    int idx = ((b * NCHUNK + c) * DINNER + d) * DSTATE + n;
    chunkA[idx] = P;
    chunkH[idx] = hp;
}

// ---------------------------------------------------------------------------
// Pass 2: sequential combine over chunks. chunkH is overwritten in place with
// the INCOMING h of each chunk. One thread per (b,d,n) = 32768.
// ---------------------------------------------------------------------------
__global__ void scan_pass2_kernel(const float* __restrict__ chunkA, float* __restrict__ chunkH) {
    int tid = blockIdx.x * 256 + threadIdx.x;
    int b = tid >> 13;
    int rem = tid & 8191;  // d*16+n
    float h = 0.f;
    for (int c = 0; c < NCHUNK; ++c) {
        int idx = (b * NCHUNK + c) * (DINNER * DSTATE) + rem;
        float Ac = chunkA[idx];
        float Hc = chunkH[idx];
        chunkH[idx] = h;          // incoming state for chunk c
        h = Ac * h + Hc;
    }
}

// ---------------------------------------------------------------------------
// Pass 3: re-scan each chunk seeded with incoming h, emit y.
// rev=1: sequence buffers are in reversed order; write output flipped back.
// ---------------------------------------------------------------------------
__global__ void scan_pass3_kernel(const float* __restrict__ delta, const float* __restrict__ u,
                                  const float* __restrict__ xdbl,
                                  const float* __restrict__ A_log, const float* __restrict__ Dv,
                                  const float* __restrict__ hin,
                                  float* __restrict__ yout, int rev) {
    int t = threadIdx.x;
    int n = t & 15;
    int dg = t >> 4;
    int d = blockIdx.x * 16 + dg;
    int c = blockIdx.y;
    int b = blockIdx.z;
    float a = -__expf(A_log[d * DSTATE + n]);
    float Dd = Dv[d];
    float h = hin[((b * NCHUNK + c) * DINNER + d) * DSTATE + n];
    int base = b * SEQ + c * CHUNK;
    for (int s = 0; s < CHUNK; ++s) {
        int row = base + s;
        float dl = delta[row * DINNER + d];
        float ul = u[row * DINNER + d];
        float Bn = xdbl[row * 64 + DTRANK + n];
        float Cn = xdbl[row * 64 + DTRANK + DSTATE + n];
        float dA = __expf(dl * a);
        h = dA * h + dl * ul * Bn;
        float yp = h * Cn;
        yp += __shfl_xor(yp, 8, 16);
        yp += __shfl_xor(yp, 4, 16);
        yp += __shfl_xor(yp, 2, 16);
        yp += __shfl_xor(yp, 1, 16);
        if (n == 0) {
            int lpos = c * CHUNK + s;
            int orow = b * SEQ + (rev ? (SEQ - 1 - lpos) : lpos);
            yout[orow * DINNER + d] = yp + Dd * ul;
        }
    }
}

// ---------------------------------------------------------------------------
// y = 0.5*(y_f + y_b)*silu(z), then LN over 512 (mnorm) -> yn
// ---------------------------------------------------------------------------
__global__ void combine_mnorm_kernel(const float* __restrict__ yf, const float* __restrict__ yb,
                                     const float* __restrict__ xz,
                                     const float* __restrict__ g, const float* __restrict__ b,
                                     float* __restrict__ yn) {
    int row = blockIdx.x;
    int t = threadIdx.x;
    __shared__ float s1[256], s2[256];
    int j0 = t, j1 = t + 256;
    float z0 = xz[row * (2 * DINNER) + DINNER + j0];
    float z1 = xz[row * (2 * DINNER) + DINNER + j1];
    float va = 0.5f * (yf[row * DINNER + j0] + yb[row * DINNER + j0]) * silu_f(z0);
    float vb = 0.5f * (yf[row * DINNER + j1] + yb[row * DINNER + j1]) * silu_f(z1);
    s1[t] = va + vb; s2[t] = va * va + vb * vb;
    __syncthreads();
    for (int s = 128; s > 0; s >>= 1) {
        if (t < s) { s1[t] += s1[t + s]; s2[t] += s2[t + s]; }
        __syncthreads();
    }
    float m = s1[0] / (float)DINNER;
    float var = s2[0] / (float)DINNER - m * m;
    float r = rsqrtf(var + 1e-5f);
    yn[row * DINNER + j0] = (va - m) * r * g[j0] + b[j0];
    yn[row * DINNER + j1] = (vb - m) * r * g[j1] + b[j1];
}

// ---------------------------------------------------------------------------
// plain LN over 512 (pnorm)
// ---------------------------------------------------------------------------
__global__ void ln512_kernel(const float* __restrict__ in,
                             const float* __restrict__ g, const float* __restrict__ b,
                             float* __restrict__ out) {
    int row = blockIdx.x;
    int t = threadIdx.x;
    __shared__ float s1[256], s2[256];
    int j0 = t, j1 = t + 256;
    float va = in[row * DMODEL + j0];
    float vb = in[row * DMODEL + j1];
    s1[t] = va + vb; s2[t] = va * va + vb * vb;
    __syncthreads();
    for (int s = 128; s > 0; s >>= 1) {
        if (t < s) { s1[t] += s1[t + s]; s2[t] += s2[t + s]; }
        __syncthreads();
    }
    float m = s1[0] / (float)DMODEL;
    float var = s2[0] / (float)DMODEL - m * m;
    float r = rsqrtf(var + 1e-5f);
    out[row * DMODEL + j0] = (va - m) * r * g[j0] + b[j0];
    out[row * DMODEL + j1] = (vb - m) * r * g[j1] + b[j1];
}

// ---------------------------------------------------------------------------
// Final: out = nan_to_num(o2)*w + x0n*(1-w) + nan_to_num(i0)  -> fp32
// ---------------------------------------------------------------------------
__global__ void final_kernel(const float* __restrict__ o2, const float* __restrict__ weight,
                             const float* __restrict__ x0n, const float* __restrict__ i0,
                             float* __restrict__ out) {
    int idx = blockIdx.x * 256 + threadIdx.x;
    float o = nan2num(o2[idx]);
    float w = weight[idx];
    float x0 = x0n[idx];
    float skip = nan2num(i0[idx]);
    out[idx] = o * w + x0 * (1.f - w) + skip;
}

extern "C" void kernel_launch(void* const* d_in, const int* in_sizes, int n_in,
                              void* d_out, int out_size, void* d_ws, size_t ws_size,
                              hipStream_t stream) {
    (void)in_sizes; (void)n_in; (void)out_size; (void)ws_size;
    const float* input0    = (const float*)d_in[0];
    const float* input1    = (const float*)d_in[1];
    const float* norm0_g   = (const float*)d_in[2];
    const float* norm0_b   = (const float*)d_in[3];
    const float* norm1_g   = (const float*)d_in[4];
    const float* norm1_b   = (const float*)d_in[5];
    const float* in_proj_w = (const float*)d_in[6];
    const float* convf_w   = (const float*)d_in[7];
    const float* convf_b   = (const float*)d_in[8];
    const float* xprojf_w  = (const float*)d_in[9];
    const float* dtf_w     = (const float*)d_in[10];
    const float* dtf_b     = (const float*)d_in[11];
    const float* A_log_f   = (const float*)d_in[12];
    const float* D_f       = (const float*)d_in[13];
    const float* convb_w   = (const float*)d_in[14];
    const float* convb_b   = (const float*)d_in[15];
    const float* xprojb_w  = (const float*)d_in[16];
    const float* dtb_w     = (const float*)d_in[17];
    const float* dtb_b     = (const float*)d_in[18];
    const float* A_log_b   = (const float*)d_in[19];
    const float* D_b       = (const float*)d_in[20];
    const float* mnorm_g   = (const float*)d_in[21];
    const float* mnorm_b   = (const float*)d_in[22];
    const float* outproj_w = (const float*)d_in[23];
    const float* pnorm_g   = (const float*)d_in[24];
    const float* pnorm_b   = (const float*)d_in[25];
    const float* projback_w= (const float*)d_in[26];
    const float* projback_b= (const float*)d_in[27];
    const float* cw_w      = (const float*)d_in[28];
    const float* cw_b      = (const float*)d_in[29];
    const float* cwln_g    = (const float*)d_in[30];
    const float* cwln_b    = (const float*)d_in[31];

    // workspace layout (floats), ~86 MB total
    float* ws = (float*)d_ws;
    float* x0n      = ws;                       // 1,048,576
    float* combined = x0n + 1048576;            // 2,097,152
    float* xz       = combined + 2097152;       // 4,194,304
    float* weight   = xz + 4194304;             // 1,048,576
    float* xdbl_f   = weight + 1048576;         //   262,144
    float* xdbl_b   = xdbl_f + 262144;          //   262,144
    float* xconv_f  = xdbl_b + 262144;          // 2,097,152
    float* xconv_b  = xconv_f + 2097152;        // 2,097,152
    float* delta_f  = xconv_b + 2097152;        // 2,097,152
    float* delta_b  = delta_f + 2097152;        // 2,097,152
    float* y_f      = delta_b + 2097152;        // 2,097,152
    float* y_b      = y_f + 2097152;            // 2,097,152
    // combined is dead between the cw GEMM and step 9 -> alias scan chunk
    // state into it (4 x 524288 floats = its exact size):
    float* chunkA_f = combined;                 // 524,288
    float* chunkH_f = combined + 524288;        // 524,288 (becomes hin_f)
    float* chunkA_b = combined + 1048576;       // 524,288
    float* chunkH_b = combined + 1572864;       // 524,288 (becomes hin_b)
    // reuse dead buffers:
    float* yn  = combined;   // written at step 9 (after scans complete)
    float* o1  = xconv_f;    // dead after scan
    float* on1 = xconv_b;    // dead after scan
    float* o2  = delta_f;    // dead after scan

    // 1. LN of both inputs -> x0n, combined
    ln01_kernel<<<NROWS, 256, 0, stream>>>(input0, input1, norm0_g, norm0_b,
                                           norm1_g, norm1_b, x0n, combined);

    // 2. xz = combined @ in_proj_w^T
    gemm_nt_kernel<<<dim3(1024 / 64, NROWS / 64), 256, 0, stream>>>(
        combined, DMODEL, in_proj_w, DMODEL, xz, 2 * DINNER, DMODEL, nullptr, 0);

    // 3. cw_pre = combined @ cw_w^T + cw_b
    gemm_nt_kernel<<<dim3(256 / 64, NROWS / 64), 256, 0, stream>>>(
        combined, DMODEL, cw_w, DMODEL, weight, CH, DMODEL, cw_b, 0);

    // 4. weight = clip(sigmoid(LN(cw_pre)))
    weight_ln_kernel<<<NROWS, 256, 0, stream>>>(weight, cwln_g, cwln_b);

    // 5. conv + silu both directions
    conv_silu_kernel<<<NROWS * DINNER / 256, 256, 0, stream>>>(xz, convf_w, convf_b, xconv_f, 0);
    conv_silu_kernel<<<NROWS * DINNER / 256, 256, 0, stream>>>(xz, convb_w, convb_b, xconv_b, 1);

    // 6. x_dbl = xconv @ xproj_w^T
    gemm_nt_kernel<<<dim3(1, NROWS / 64), 256, 0, stream>>>(
        xconv_f, DINNER, xprojf_w, DINNER, xdbl_f, 64, DINNER, nullptr, 0);
    gemm_nt_kernel<<<dim3(1, NROWS / 64), 256, 0, stream>>>(
        xconv_b, DINNER, xprojb_w, DINNER, xdbl_b, 64, DINNER, nullptr, 0);

    // 7. delta = softplus(x_dbl[:, :32] @ dt_w^T + dt_b)
    gemm_nt_kernel<<<dim3(512 / 64, NROWS / 64), 256, 0, stream>>>(
        xdbl_f, 64, dtf_w, DTRANK, delta_f, DINNER, DTRANK, dtf_b, 1);
    gemm_nt_kernel<<<dim3(512 / 64, NROWS / 64), 256, 0, stream>>>(
        xdbl_b, 64, dtb_w, DTRANK, delta_b, DINNER, DTRANK, dtb_b, 1);

    // 8. chunked selective scan, both directions
    dim3 sgrid(DINNER / 16, NCHUNK, BDIM);
    scan_pass1_kernel<<<sgrid, 256, 0, stream>>>(delta_f, xconv_f, xdbl_f, A_log_f,
                                                 chunkA_f, chunkH_f);
    scan_pass1_kernel<<<sgrid, 256, 0, stream>>>(delta_b, xconv_b, xdbl_b, A_log_b,
                                                 chunkA_b, chunkH_b);
    scan_pass2_kernel<<<128, 256, 0, stream>>>(chunkA_f, chunkH_f);
    scan_pass2_kernel<<<128, 256, 0, stream>>>(chunkA_b, chunkH_b);
    scan_pass3_kernel<<<sgrid, 256, 0, stream>>>(delta_f, xconv_f, xdbl_f, A_log_f, D_f,
                                                 chunkH_f, y_f, 0);
    scan_pass3_kernel<<<sgrid, 256, 0, stream>>>(delta_b, xconv_b, xdbl_b, A_log_b, D_b,
                                                 chunkH_b, y_b, 1);

    // 9. combine + mnorm LN -> yn
    combine_mnorm_kernel<<<NROWS, 256, 0, stream>>>(y_f, y_b, xz, mnorm_g, mnorm_b, yn);

    // 10. o1 = yn @ outproj_w^T
    gemm_nt_kernel<<<dim3(512 / 64, NROWS / 64), 256, 0, stream>>>(
        yn, DINNER, outproj_w, DINNER, o1, DMODEL, DINNER, nullptr, 0);

    // 11. pnorm LN -> on1
    ln512_kernel<<<NROWS, 256, 0, stream>>>(o1, pnorm_g, pnorm_b, on1);

    // 12. o2 = on1 @ projback_w^T + projback_b
    gemm_nt_kernel<<<dim3(256 / 64, NROWS / 64), 256, 0, stream>>>(
        on1, DMODEL, projback_w, DMODEL, o2, CH, DMODEL, projback_b, 0);

    // 13. final blend + skip -> fp32 out
    final_kernel<<<NROWS, 256, 0, stream>>>(o2, weight, x0n, input0, (float*)d_out);
}

// Round 4
// 455.956 us; speedup vs baseline: 3.1369x; 1.1737x over previous
//
#include <hip/hip_runtime.h>

#define BDIM 4
#define SEQ 1024
#define CH 256
#define DMODEL 512
#define DINNER 512
#define DSTATE 16
#define DTRANK 32
#define NROWS (BDIM * SEQ)   // 4096
#define NCHUNK 16
#define CHUNK (SEQ / NCHUNK) // 64

typedef unsigned short ushort_t;

__device__ __forceinline__ float nan2num(float x) {
    if (isnan(x)) return 0.f;
    if (isinf(x)) return x > 0.f ? 1.f : -1.f;
    return x;
}

__device__ __forceinline__ float silu_f(float x) { return x / (1.f + __expf(-x)); }
__device__ __forceinline__ float sigmoid_f(float x) { return 1.f / (1.f + __expf(-x)); }
__device__ __forceinline__ float softplus_f(float x) {
    return x > 20.f ? x : log1pf(__expf(x));
}

// fp32 -> bf16 with round-to-nearest-even
__device__ __forceinline__ ushort_t f2bf(float x) {
    union { float f; unsigned u; } v; v.f = x;
    unsigned r = v.u + 0x7fff + ((v.u >> 16) & 1);
    return (ushort_t)(r >> 16);
}

using bf16x8 = __attribute__((ext_vector_type(8))) __bf16;
using f32x4  = __attribute__((ext_vector_type(4))) float;

// ---------------------------------------------------------------------------
// Kernel 1: nan_to_num + LN(i0), LN(i1) -> x0n (B*N,256) and combined (B*N,512)
// ---------------------------------------------------------------------------
__global__ void ln01_kernel(const float* __restrict__ i0, const float* __restrict__ i1,
                            const float* __restrict__ g0, const float* __restrict__ b0,
                            const float* __restrict__ g1, const float* __restrict__ b1,
                            float* __restrict__ x0n, float* __restrict__ combined) {
    int row = blockIdx.x;
    int t = threadIdx.x;
    __shared__ float s1[256], s2[256];

    float v0 = nan2num(i0[row * CH + t]);
    s1[t] = v0; s2[t] = v0 * v0;
    __syncthreads();
    for (int s = 128; s > 0; s >>= 1) {
        if (t < s) { s1[t] += s1[t + s]; s2[t] += s2[t + s]; }
        __syncthreads();
    }
    float m = s1[0] / (float)CH;
    float var = s2[0] / (float)CH - m * m;
    float r = rsqrtf(var + 1e-5f);
    float o0 = (v0 - m) * r * g0[t] + b0[t];
    x0n[row * CH + t] = o0;
    combined[row * DMODEL + t] = o0;
    __syncthreads();

    float v1 = nan2num(i1[row * CH + t]);
    s1[t] = v1; s2[t] = v1 * v1;
    __syncthreads();
    for (int s = 128; s > 0; s >>= 1) {
        if (t < s) { s1[t] += s1[t + s]; s2[t] += s2[t + s]; }
        __syncthreads();
    }
    m = s1[0] / (float)CH;
    var = s2[0] / (float)CH - m * m;
    r = rsqrtf(var + 1e-5f);
    float o1 = (v1 - m) * r * g1[t] + b1[t];
    combined[row * DMODEL + CH + t] = o1;
}

// ---------------------------------------------------------------------------
// bf16-MFMA GEMM (NT): C[m,n] = sum_k A[m,k]*W[n,k] (+bias[n]) (+softplus)
// A, W fp32 in HBM; converted to bf16 during LDS staging; fp32 accumulate.
// Tile: 64x64, BK=32. Block = 256 threads = 4 waves, each wave 32x32.
// Requires M%64==0, N%64==0, K%32==0, lda/ldw%4==0.
// LDS rows padded to 40 shorts (80 B = 5*16 B): b128-aligned, 2-way bank
// aliasing only (free per m136).
// ---------------------------------------------------------------------------
template<int ACT>
__global__ void gemm_mfma_kernel(const float* __restrict__ A, int lda,
                                 const float* __restrict__ W, int ldw,
                                 float* __restrict__ C, int ldc,
                                 int K, const float* __restrict__ bias) {
    __shared__ ushort_t As[64][40];
    __shared__ ushort_t Ws[64][40];
    const int t = threadIdx.x;
    const int m0 = blockIdx.y * 64;
    const int n0 = blockIdx.x * 64;
    const int w = t >> 6;
    const int lane = t & 63;
    const int lane16 = lane & 15;
    const int quad = lane >> 4;
    const int wr = (w >> 1) * 32;   // wave row offset in tile
    const int wc = (w & 1) * 32;    // wave col offset in tile

    f32x4 acc[2][2] = {};

    for (int k0 = 0; k0 < K; k0 += 32) {
#pragma unroll
        for (int i = 0; i < 2; ++i) {
            int flat = i * 256 + t;          // 0..511
            int row = flat >> 3;             // 0..63
            int c4 = flat & 7;               // 0..7 (float4 index)
            float4 av = *(const float4*)(A + (m0 + row) * lda + k0 + c4 * 4);
            float4 wv = *(const float4*)(W + (n0 + row) * ldw + k0 + c4 * 4);
            ushort4 a4 = make_ushort4(f2bf(av.x), f2bf(av.y), f2bf(av.z), f2bf(av.w));
            ushort4 w4 = make_ushort4(f2bf(wv.x), f2bf(wv.y), f2bf(wv.z), f2bf(wv.w));
            *(ushort4*)&As[row][c4 * 4] = a4;
            *(ushort4*)&Ws[row][c4 * 4] = w4;
        }
        __syncthreads();

        bf16x8 af[2], bfr[2];
#pragma unroll
        for (int i = 0; i < 2; ++i) {
            af[i]  = *(bf16x8*)&As[wr + i * 16 + lane16][quad * 8];
            bfr[i] = *(bf16x8*)&Ws[wc + i * 16 + lane16][quad * 8];
        }
#pragma unroll
        for (int i = 0; i < 2; ++i)
#pragma unroll
            for (int j = 0; j < 2; ++j)
                acc[i][j] = __builtin_amdgcn_mfma_f32_16x16x32_bf16(af[i], bfr[j], acc[i][j], 0, 0, 0);
        __syncthreads();
    }

    // D layout: col = lane16, row = quad*4 + r (m89/m91-verified)
#pragma unroll
    for (int j = 0; j < 2; ++j) {
        int col = n0 + wc + j * 16 + lane16;
        float bv = bias ? bias[col] : 0.f;
#pragma unroll
        for (int i = 0; i < 2; ++i) {
#pragma unroll
            for (int r = 0; r < 4; ++r) {
                int row = m0 + wr + i * 16 + quad * 4 + r;
                float c = acc[i][j][r] + bv;
                if (ACT == 1) c = softplus_f(c);
                C[row * ldc + col] = c;
            }
        }
    }
}

// ---------------------------------------------------------------------------
// weight = clip(sigmoid(LN(cw_pre)), 0.01, 0.99), in place (row len 256)
// ---------------------------------------------------------------------------
__global__ void weight_ln_kernel(float* __restrict__ wbuf,
                                 const float* __restrict__ g, const float* __restrict__ b) {
    int row = blockIdx.x;
    int t = threadIdx.x;
    __shared__ float s1[256], s2[256];
    float v = wbuf[row * CH + t];
    s1[t] = v; s2[t] = v * v;
    __syncthreads();
    for (int s = 128; s > 0; s >>= 1) {
        if (t < s) { s1[t] += s1[t + s]; s2[t] += s2[t + s]; }
        __syncthreads();
    }
    float m = s1[0] / (float)CH;
    float var = s2[0] / (float)CH - m * m;
    float r = rsqrtf(var + 1e-5f);
    float o = sigmoid_f((v - m) * r * g[t] + b[t]);
    o = fminf(fmaxf(o, 0.01f), 0.99f);
    wbuf[row * CH + t] = o;
}

// ---------------------------------------------------------------------------
// depthwise causal conv (width 4) + bias + silu
// ---------------------------------------------------------------------------
__global__ void conv_silu_kernel(const float* __restrict__ xz,
                                 const float* __restrict__ w, const float* __restrict__ wb,
                                 float* __restrict__ out, int rev) {
    int flat = blockIdx.x * 256 + threadIdx.x;   // over 4096*512
    int d = flat & (DINNER - 1);
    int row = flat >> 9;
    int l = row & (SEQ - 1);
    int b = row >> 10;
    float acc = wb[d];
#pragma unroll
    for (int k = 0; k < 4; ++k) {
        int j = l - 3 + k;
        if (j >= 0) {
            int lp = rev ? (SEQ - 1 - j) : j;
            acc += xz[(b * SEQ + lp) * (2 * DINNER) + d] * w[d * 4 + k];
        }
    }
    out[flat] = silu_f(acc);
}

// ---------------------------------------------------------------------------
// Chunked selective scan, pass 1: per-chunk (prodA, partial h).
// block = 256 = 16 d x 16 n ; grid = (DINNER/16, NCHUNK, B)
// ---------------------------------------------------------------------------
__global__ void scan_pass1_kernel(const float* __restrict__ delta, const float* __restrict__ u,
                                  const float* __restrict__ xdbl,
                                  const float* __restrict__ A_log,
                                  float* __restrict__ chunkA, float* __restrict__ chunkH) {
    int t = threadIdx.x;
    int n = t & 15;
    int dg = t >> 4;
    int d = blockIdx.x * 16 + dg;
    int c = blockIdx.y;
    int b = blockIdx.z;
    float a = -__expf(A_log[d * DSTATE + n]);
    float P = 1.f, hp = 0.f;
    int base = b * SEQ + c * CHUNK;
    for (int s = 0; s < CHUNK; ++s) {
        int row = base + s;
        float dl = delta[row * DINNER + d];
        float ul = u[row * DINNER + d];
        float Bn = xdbl[row * 64 + DTRANK + n];
        float dA = __expf(dl * a);
        hp = dA * hp + dl * ul * Bn;
        P *= dA;
    }
    int idx = ((b * NCHUNK + c) * DINNER + d) * DSTATE + n;
    chunkA[idx] = P;
    chunkH[idx] = hp;
}

// ---------------------------------------------------------------------------
// Pass 2: sequential combine over chunks (in place -> incoming h per chunk)
// ---------------------------------------------------------------------------
__global__ void scan_pass2_kernel(const float* __restrict__ chunkA, float* __restrict__ chunkH) {
    int tid = blockIdx.x * 256 + threadIdx.x;
    int b = tid >> 13;
    int rem = tid & 8191;  // d*16+n
    float h = 0.f;
    for (int c = 0; c < NCHUNK; ++c) {
        int idx = (b * NCHUNK + c) * (DINNER * DSTATE) + rem;
        float Ac = chunkA[idx];
        float Hc = chunkH[idx];
        chunkH[idx] = h;
        h = Ac * h + Hc;
    }
}

// ---------------------------------------------------------------------------
// Pass 3: re-scan each chunk seeded with incoming h, emit y.
// ---------------------------------------------------------------------------
__global__ void scan_pass3_kernel(const float* __restrict__ delta, const float* __restrict__ u,
                                  const float* __restrict__ xdbl,
                                  const float* __restrict__ A_log, const float* __restrict__ Dv,
                                  const float* __restrict__ hin,
                                  float* __restrict__ yout, int rev) {
    int t = threadIdx.x;
    int n = t & 15;
    int dg = t >> 4;
    int d = blockIdx.x * 16 + dg;
    int c = blockIdx.y;
    int b = blockIdx.z;
    float a = -__expf(A_log[d * DSTATE + n]);
    float Dd = Dv[d];
    float h = hin[((b * NCHUNK + c) * DINNER + d) * DSTATE + n];
    int base = b * SEQ + c * CHUNK;
    for (int s = 0; s < CHUNK; ++s) {
        int row = base + s;
        float dl = delta[row * DINNER + d];
        float ul = u[row * DINNER + d];
        float Bn = xdbl[row * 64 + DTRANK + n];
        float Cn = xdbl[row * 64 + DTRANK + DSTATE + n];
        float dA = __expf(dl * a);
        h = dA * h + dl * ul * Bn;
        float yp = h * Cn;
        yp += __shfl_xor(yp, 8, 16);
        yp += __shfl_xor(yp, 4, 16);
        yp += __shfl_xor(yp, 2, 16);
        yp += __shfl_xor(yp, 1, 16);
        if (n == 0) {
            int lpos = c * CHUNK + s;
            int orow = b * SEQ + (rev ? (SEQ - 1 - lpos) : lpos);
            yout[orow * DINNER + d] = yp + Dd * ul;
        }
    }
}

// ---------------------------------------------------------------------------
// y = 0.5*(y_f + y_b)*silu(z), then LN over 512 (mnorm) -> yn
// ---------------------------------------------------------------------------
__global__ void combine_mnorm_kernel(const float* __restrict__ yf, const float* __restrict__ yb,
                                     const float* __restrict__ xz,
                                     const float* __restrict__ g, const float* __restrict__ b,
                                     float* __restrict__ yn) {
    int row = blockIdx.x;
    int t = threadIdx.x;
    __shared__ float s1[256], s2[256];
    int j0 = t, j1 = t + 256;
    float z0 = xz[row * (2 * DINNER) + DINNER + j0];
    float z1 = xz[row * (2 * DINNER) + DINNER + j1];
    float va = 0.5f * (yf[row * DINNER + j0] + yb[row * DINNER + j0]) * silu_f(z0);
    float vb = 0.5f * (yf[row * DINNER + j1] + yb[row * DINNER + j1]) * silu_f(z1);
    s1[t] = va + vb; s2[t] = va * va + vb * vb;
    __syncthreads();
    for (int s = 128; s > 0; s >>= 1) {
        if (t < s) { s1[t] += s1[t + s]; s2[t] += s2[t + s]; }
        __syncthreads();
    }
    float m = s1[0] / (float)DINNER;
    float var = s2[0] / (float)DINNER - m * m;
    float r = rsqrtf(var + 1e-5f);
    yn[row * DINNER + j0] = (va - m) * r * g[j0] + b[j0];
    yn[row * DINNER + j1] = (vb - m) * r * g[j1] + b[j1];
}

// ---------------------------------------------------------------------------
// plain LN over 512 (pnorm)
// ---------------------------------------------------------------------------
__global__ void ln512_kernel(const float* __restrict__ in,
                             const float* __restrict__ g, const float* __restrict__ b,
                             float* __restrict__ out) {
    int row = blockIdx.x;
    int t = threadIdx.x;
    __shared__ float s1[256], s2[256];
    int j0 = t, j1 = t + 256;
    float va = in[row * DMODEL + j0];
    float vb = in[row * DMODEL + j1];
    s1[t] = va + vb; s2[t] = va * va + vb * vb;
    __syncthreads();
    for (int s = 128; s > 0; s >>= 1) {
        if (t < s) { s1[t] += s1[t + s]; s2[t] += s2[t + s]; }
        __syncthreads();
    }
    float m = s1[0] / (float)DMODEL;
    float var = s2[0] / (float)DMODEL - m * m;
    float r = rsqrtf(var + 1e-5f);
    out[row * DMODEL + j0] = (va - m) * r * g[j0] + b[j0];
    out[row * DMODEL + j1] = (vb - m) * r * g[j1] + b[j1];
}

// ---------------------------------------------------------------------------
// Final: out = nan_to_num(o2)*w + x0n*(1-w) + nan_to_num(i0)  -> fp32
// ---------------------------------------------------------------------------
__global__ void final_kernel(const float* __restrict__ o2, const float* __restrict__ weight,
                             const float* __restrict__ x0n, const float* __restrict__ i0,
                             float* __restrict__ out) {
    int idx = blockIdx.x * 256 + threadIdx.x;
    float o = nan2num(o2[idx]);
    float w = weight[idx];
    float x0 = x0n[idx];
    float skip = nan2num(i0[idx]);
    out[idx] = o * w + x0 * (1.f - w) + skip;
}

extern "C" void kernel_launch(void* const* d_in, const int* in_sizes, int n_in,
                              void* d_out, int out_size, void* d_ws, size_t ws_size,
                              hipStream_t stream) {
    (void)in_sizes; (void)n_in; (void)out_size; (void)ws_size;
    const float* input0    = (const float*)d_in[0];
    const float* input1    = (const float*)d_in[1];
    const float* norm0_g   = (const float*)d_in[2];
    const float* norm0_b   = (const float*)d_in[3];
    const float* norm1_g   = (const float*)d_in[4];
    const float* norm1_b   = (const float*)d_in[5];
    const float* in_proj_w = (const float*)d_in[6];
    const float* convf_w   = (const float*)d_in[7];
    const float* convf_b   = (const float*)d_in[8];
    const float* xprojf_w  = (const float*)d_in[9];
    const float* dtf_w     = (const float*)d_in[10];
    const float* dtf_b     = (const float*)d_in[11];
    const float* A_log_f   = (const float*)d_in[12];
    const float* D_f       = (const float*)d_in[13];
    const float* convb_w   = (const float*)d_in[14];
    const float* convb_b   = (const float*)d_in[15];
    const float* xprojb_w  = (const float*)d_in[16];
    const float* dtb_w     = (const float*)d_in[17];
    const float* dtb_b     = (const float*)d_in[18];
    const float* A_log_b   = (const float*)d_in[19];
    const float* D_b       = (const float*)d_in[20];
    const float* mnorm_g   = (const float*)d_in[21];
    const float* mnorm_b   = (const float*)d_in[22];
    const float* outproj_w = (const float*)d_in[23];
    const float* pnorm_g   = (const float*)d_in[24];
    const float* pnorm_b   = (const float*)d_in[25];
    const float* projback_w= (const float*)d_in[26];
    const float* projback_b= (const float*)d_in[27];
    const float* cw_w      = (const float*)d_in[28];
    const float* cw_b      = (const float*)d_in[29];
    const float* cwln_g    = (const float*)d_in[30];
    const float* cwln_b    = (const float*)d_in[31];

    // workspace layout (floats), ~86 MB total
    float* ws = (float*)d_ws;
    float* x0n      = ws;                       // 1,048,576
    float* combined = x0n + 1048576;            // 2,097,152
    float* xz       = combined + 2097152;       // 4,194,304
    float* weight   = xz + 4194304;             // 1,048,576
    float* xdbl_f   = weight + 1048576;         //   262,144
    float* xdbl_b   = xdbl_f + 262144;          //   262,144
    float* xconv_f  = xdbl_b + 262144;          // 2,097,152
    float* xconv_b  = xconv_f + 2097152;        // 2,097,152
    float* delta_f  = xconv_b + 2097152;        // 2,097,152
    float* delta_b  = delta_f + 2097152;        // 2,097,152
    float* y_f      = delta_b + 2097152;        // 2,097,152
    float* y_b      = y_f + 2097152;            // 2,097,152
    // combined is dead between the cw GEMM and step 9 -> alias chunk state:
    float* chunkA_f = combined;                 // 524,288
    float* chunkH_f = combined + 524288;        // 524,288
    float* chunkA_b = combined + 1048576;       // 524,288
    float* chunkH_b = combined + 1572864;       // 524,288
    float* yn  = combined;   // written at step 9 (after scans complete)
    float* o1  = xconv_f;    // dead after scan
    float* on1 = xconv_b;    // dead after scan
    float* o2  = delta_f;    // dead after scan

    // 1. LN of both inputs -> x0n, combined
    ln01_kernel<<<NROWS, 256, 0, stream>>>(input0, input1, norm0_g, norm0_b,
                                           norm1_g, norm1_b, x0n, combined);

    // 2. xz = combined @ in_proj_w^T
    gemm_mfma_kernel<0><<<dim3(1024 / 64, NROWS / 64), 256, 0, stream>>>(
        combined, DMODEL, in_proj_w, DMODEL, xz, 2 * DINNER, DMODEL, nullptr);

    // 3. cw_pre = combined @ cw_w^T + cw_b
    gemm_mfma_kernel<0><<<dim3(256 / 64, NROWS / 64), 256, 0, stream>>>(
        combined, DMODEL, cw_w, DMODEL, weight, CH, DMODEL, cw_b);

    // 4. weight = clip(sigmoid(LN(cw_pre)))
    weight_ln_kernel<<<NROWS, 256, 0, stream>>>(weight, cwln_g, cwln_b);

    // 5. conv + silu both directions
    conv_silu_kernel<<<NROWS * DINNER / 256, 256, 0, stream>>>(xz, convf_w, convf_b, xconv_f, 0);
    conv_silu_kernel<<<NROWS * DINNER / 256, 256, 0, stream>>>(xz, convb_w, convb_b, xconv_b, 1);

    // 6. x_dbl = xconv @ xproj_w^T  (N=64)
    gemm_mfma_kernel<0><<<dim3(1, NROWS / 64), 256, 0, stream>>>(
        xconv_f, DINNER, xprojf_w, DINNER, xdbl_f, 64, DINNER, nullptr);
    gemm_mfma_kernel<0><<<dim3(1, NROWS / 64), 256, 0, stream>>>(
        xconv_b, DINNER, xprojb_w, DINNER, xdbl_b, 64, DINNER, nullptr);

    // 7. delta = softplus(x_dbl[:, :32] @ dt_w^T + dt_b)   (K=32)
    gemm_mfma_kernel<1><<<dim3(512 / 64, NROWS / 64), 256, 0, stream>>>(
        xdbl_f, 64, dtf_w, DTRANK, delta_f, DINNER, DTRANK, dtf_b);
    gemm_mfma_kernel<1><<<dim3(512 / 64, NROWS / 64), 256, 0, stream>>>(
        xdbl_b, 64, dtb_w, DTRANK, delta_b, DINNER, DTRANK, dtb_b);

    // 8. chunked selective scan, both directions
    dim3 sgrid(DINNER / 16, NCHUNK, BDIM);
    scan_pass1_kernel<<<sgrid, 256, 0, stream>>>(delta_f, xconv_f, xdbl_f, A_log_f,
                                                 chunkA_f, chunkH_f);
    scan_pass1_kernel<<<sgrid, 256, 0, stream>>>(delta_b, xconv_b, xdbl_b, A_log_b,
                                                 chunkA_b, chunkH_b);
    scan_pass2_kernel<<<128, 256, 0, stream>>>(chunkA_f, chunkH_f);
    scan_pass2_kernel<<<128, 256, 0, stream>>>(chunkA_b, chunkH_b);
    scan_pass3_kernel<<<sgrid, 256, 0, stream>>>(delta_f, xconv_f, xdbl_f, A_log_f, D_f,
                                                 chunkH_f, y_f, 0);
    scan_pass3_kernel<<<sgrid, 256, 0, stream>>>(delta_b, xconv_b, xdbl_b, A_log_b, D_b,
                                                 chunkH_b, y_b, 1);

    // 9. combine + mnorm LN -> yn
    combine_mnorm_kernel<<<NROWS, 256, 0, stream>>>(y_f, y_b, xz, mnorm_g, mnorm_b, yn);

    // 10. o1 = yn @ outproj_w^T
    gemm_mfma_kernel<0><<<dim3(512 / 64, NROWS / 64), 256, 0, stream>>>(
        yn, DINNER, outproj_w, DINNER, o1, DMODEL, DINNER, nullptr);

    // 11. pnorm LN -> on1
    ln512_kernel<<<NROWS, 256, 0, stream>>>(o1, pnorm_g, pnorm_b, on1);

    // 12. o2 = on1 @ projback_w^T + projback_b
    gemm_mfma_kernel<0><<<dim3(256 / 64, NROWS / 64), 256, 0, stream>>>(
        on1, DMODEL, projback_w, DMODEL, o2, CH, DMODEL, projback_b);

    // 13. final blend + skip -> fp32 out
    final_kernel<<<NROWS, 256, 0, stream>>>(o2, weight, x0n, input0, (float*)d_out);
}

// Round 5
// 373.002 us; speedup vs baseline: 3.8345x; 1.2224x over previous
//
#include <hip/hip_runtime.h>

#define BDIM 4
#define SEQ 1024
#define CH 256
#define DMODEL 512
#define DINNER 512
#define DSTATE 16
#define DTRANK 32
#define NROWS (BDIM * SEQ)   // 4096
#define NCHUNK 16
#define CHUNK (SEQ / NCHUNK) // 64

typedef unsigned short ushort_t;

__device__ __forceinline__ float nan2num(float x) {
    if (isnan(x)) return 0.f;
    if (isinf(x)) return x > 0.f ? 1.f : -1.f;
    return x;
}

__device__ __forceinline__ float silu_f(float x) { return x / (1.f + __expf(-x)); }
__device__ __forceinline__ float sigmoid_f(float x) { return 1.f / (1.f + __expf(-x)); }
__device__ __forceinline__ float softplus_f(float x) {
    return x > 20.f ? x : log1pf(__expf(x));
}

// fp32 -> bf16 round-to-nearest-even
__device__ __forceinline__ ushort_t f2bf(float x) {
    union { float f; unsigned u; } v; v.f = x;
    unsigned r = v.u + 0x7fff + ((v.u >> 16) & 1);
    return (ushort_t)(r >> 16);
}

using bf16x8 = __attribute__((ext_vector_type(8))) __bf16;
using f32x4  = __attribute__((ext_vector_type(4))) float;

// wave-wide (64-lane) reduction of (s,q)
__device__ __forceinline__ void wave_reduce2(float& s, float& q) {
#pragma unroll
    for (int m = 32; m > 0; m >>= 1) {
        s += __shfl_xor(s, m);
        q += __shfl_xor(q, m);
    }
}

// ---------------------------------------------------------------------------
// ln01: wave-per-row LN of i0 and i1 -> x0n, combined. grid 1024 x 256thr.
// ---------------------------------------------------------------------------
__global__ __launch_bounds__(256) void ln01_kernel(
        const float* __restrict__ i0, const float* __restrict__ i1,
        const float* __restrict__ g0, const float* __restrict__ b0,
        const float* __restrict__ g1, const float* __restrict__ b1,
        float* __restrict__ x0n, float* __restrict__ combined) {
    int w = threadIdx.x >> 6, lane = threadIdx.x & 63;
    int row = blockIdx.x * 4 + w;

    // --- input0 ---
    float4 v = ((const float4*)(i0 + row * CH))[lane];
    v.x = nan2num(v.x); v.y = nan2num(v.y); v.z = nan2num(v.z); v.w = nan2num(v.w);
    float s = v.x + v.y + v.z + v.w;
    float q = v.x * v.x + v.y * v.y + v.z * v.z + v.w * v.w;
    wave_reduce2(s, q);
    float m = s / (float)CH;
    float r = rsqrtf(q / (float)CH - m * m + 1e-5f);
    float4 g = ((const float4*)g0)[lane];
    float4 bb = ((const float4*)b0)[lane];
    float4 o;
    o.x = (v.x - m) * r * g.x + bb.x;
    o.y = (v.y - m) * r * g.y + bb.y;
    o.z = (v.z - m) * r * g.z + bb.z;
    o.w = (v.w - m) * r * g.w + bb.w;
    ((float4*)(x0n + row * CH))[lane] = o;
    ((float4*)(combined + row * DMODEL))[lane] = o;

    // --- input1 ---
    v = ((const float4*)(i1 + row * CH))[lane];
    v.x = nan2num(v.x); v.y = nan2num(v.y); v.z = nan2num(v.z); v.w = nan2num(v.w);
    s = v.x + v.y + v.z + v.w;
    q = v.x * v.x + v.y * v.y + v.z * v.z + v.w * v.w;
    wave_reduce2(s, q);
    m = s / (float)CH;
    r = rsqrtf(q / (float)CH - m * m + 1e-5f);
    g = ((const float4*)g1)[lane];
    bb = ((const float4*)b1)[lane];
    o.x = (v.x - m) * r * g.x + bb.x;
    o.y = (v.y - m) * r * g.y + bb.y;
    o.z = (v.z - m) * r * g.z + bb.z;
    o.w = (v.w - m) * r * g.w + bb.w;
    ((float4*)(combined + row * DMODEL + CH))[lane] = o;
}

// ---------------------------------------------------------------------------
// bf16-MFMA GEMM (NT), dual-batch via blockIdx.z.
// C[m,n] = sum_k A[m,k]*W[n,k] (+bias) (+softplus if ACT==1)
// Tile 64x64, BK=32, 4 waves. fp32->bf16 conversion during staging.
// ---------------------------------------------------------------------------
template<int ACT>
__global__ __launch_bounds__(256) void gemm_mfma_kernel(
        const float* __restrict__ A0, const float* __restrict__ A1, int lda,
        const float* __restrict__ W0, const float* __restrict__ W1, int ldw,
        float* __restrict__ C0, float* __restrict__ C1, int ldc,
        int K, const float* __restrict__ bias0, const float* __restrict__ bias1) {
    const float* A = blockIdx.z ? A1 : A0;
    const float* W = blockIdx.z ? W1 : W0;
    float* C = blockIdx.z ? C1 : C0;
    const float* bias = blockIdx.z ? bias1 : bias0;

    __shared__ ushort_t As[64][40];
    __shared__ ushort_t Ws[64][40];
    const int t = threadIdx.x;
    const int m0 = blockIdx.y * 64;
    const int n0 = blockIdx.x * 64;
    const int w = t >> 6;
    const int lane = t & 63;
    const int lane16 = lane & 15;
    const int quad = lane >> 4;
    const int wr = (w >> 1) * 32;
    const int wc = (w & 1) * 32;

    const int srow = t >> 2;          // 0..63
    const int sc8 = (t & 3) * 8;      // 0,8,16,24

    f32x4 acc[2][2] = {};

    for (int k0 = 0; k0 < K; k0 += 32) {
        float4 a0 = *(const float4*)(A + (m0 + srow) * lda + k0 + sc8);
        float4 a1 = *(const float4*)(A + (m0 + srow) * lda + k0 + sc8 + 4);
        float4 w0 = *(const float4*)(W + (n0 + srow) * ldw + k0 + sc8);
        float4 w1 = *(const float4*)(W + (n0 + srow) * ldw + k0 + sc8 + 4);
        *(ushort4*)&As[srow][sc8]     = make_ushort4(f2bf(a0.x), f2bf(a0.y), f2bf(a0.z), f2bf(a0.w));
        *(ushort4*)&As[srow][sc8 + 4] = make_ushort4(f2bf(a1.x), f2bf(a1.y), f2bf(a1.z), f2bf(a1.w));
        *(ushort4*)&Ws[srow][sc8]     = make_ushort4(f2bf(w0.x), f2bf(w0.y), f2bf(w0.z), f2bf(w0.w));
        *(ushort4*)&Ws[srow][sc8 + 4] = make_ushort4(f2bf(w1.x), f2bf(w1.y), f2bf(w1.z), f2bf(w1.w));
        __syncthreads();

        bf16x8 af[2], bfr[2];
#pragma unroll
        for (int i = 0; i < 2; ++i) {
            af[i]  = *(bf16x8*)&As[wr + i * 16 + lane16][quad * 8];
            bfr[i] = *(bf16x8*)&Ws[wc + i * 16 + lane16][quad * 8];
        }
#pragma unroll
        for (int i = 0; i < 2; ++i)
#pragma unroll
            for (int j = 0; j < 2; ++j)
                acc[i][j] = __builtin_amdgcn_mfma_f32_16x16x32_bf16(af[i], bfr[j], acc[i][j], 0, 0, 0);
        __syncthreads();
    }

#pragma unroll
    for (int j = 0; j < 2; ++j) {
        int col = n0 + wc + j * 16 + lane16;
        float bv = bias ? bias[col] : 0.f;
#pragma unroll
        for (int i = 0; i < 2; ++i) {
#pragma unroll
            for (int r = 0; r < 4; ++r) {
                int row = m0 + wr + i * 16 + quad * 4 + r;
                float c = acc[i][j][r] + bv;
                if (ACT == 1) c = softplus_f(c);
                C[row * ldc + col] = c;
            }
        }
    }
}

// ---------------------------------------------------------------------------
// projback GEMM + final blend fused:
// o2 = on1 @ projback_w^T + pb;  out = nan2num(o2)*wgt + x0n*(1-wgt) + nan2num(i0)
// ---------------------------------------------------------------------------
__global__ __launch_bounds__(256) void gemm_projback_final_kernel(
        const float* __restrict__ A, int lda,
        const float* __restrict__ W, int ldw,
        int K, const float* __restrict__ bias,
        const float* __restrict__ wgt, const float* __restrict__ x0n,
        const float* __restrict__ i0, float* __restrict__ out) {
    __shared__ ushort_t As[64][40];
    __shared__ ushort_t Ws[64][40];
    const int t = threadIdx.x;
    const int m0 = blockIdx.y * 64;
    const int n0 = blockIdx.x * 64;
    const int w = t >> 6;
    const int lane = t & 63;
    const int lane16 = lane & 15;
    const int quad = lane >> 4;
    const int wr = (w >> 1) * 32;
    const int wc = (w & 1) * 32;
    const int srow = t >> 2;
    const int sc8 = (t & 3) * 8;

    f32x4 acc[2][2] = {};

    for (int k0 = 0; k0 < K; k0 += 32) {
        float4 a0 = *(const float4*)(A + (m0 + srow) * lda + k0 + sc8);
        float4 a1 = *(const float4*)(A + (m0 + srow) * lda + k0 + sc8 + 4);
        float4 w0 = *(const float4*)(W + (n0 + srow) * ldw + k0 + sc8);
        float4 w1 = *(const float4*)(W + (n0 + srow) * ldw + k0 + sc8 + 4);
        *(ushort4*)&As[srow][sc8]     = make_ushort4(f2bf(a0.x), f2bf(a0.y), f2bf(a0.z), f2bf(a0.w));
        *(ushort4*)&As[srow][sc8 + 4] = make_ushort4(f2bf(a1.x), f2bf(a1.y), f2bf(a1.z), f2bf(a1.w));
        *(ushort4*)&Ws[srow][sc8]     = make_ushort4(f2bf(w0.x), f2bf(w0.y), f2bf(w0.z), f2bf(w0.w));
        *(ushort4*)&Ws[srow][sc8 + 4] = make_ushort4(f2bf(w1.x), f2bf(w1.y), f2bf(w1.z), f2bf(w1.w));
        __syncthreads();

        bf16x8 af[2], bfr[2];
#pragma unroll
        for (int i = 0; i < 2; ++i) {
            af[i]  = *(bf16x8*)&As[wr + i * 16 + lane16][quad * 8];
            bfr[i] = *(bf16x8*)&Ws[wc + i * 16 + lane16][quad * 8];
        }
#pragma unroll
        for (int i = 0; i < 2; ++i)
#pragma unroll
            for (int j = 0; j < 2; ++j)
                acc[i][j] = __builtin_amdgcn_mfma_f32_16x16x32_bf16(af[i], bfr[j], acc[i][j], 0, 0, 0);
        __syncthreads();
    }

#pragma unroll
    for (int j = 0; j < 2; ++j) {
        int col = n0 + wc + j * 16 + lane16;
        float bv = bias[col];
#pragma unroll
        for (int i = 0; i < 2; ++i) {
#pragma unroll
            for (int r = 0; r < 4; ++r) {
                int row = m0 + wr + i * 16 + quad * 4 + r;
                float o = nan2num(acc[i][j][r] + bv);
                float wv = wgt[row * CH + col];
                float xv = x0n[row * CH + col];
                float sk = nan2num(i0[row * CH + col]);
                out[row * CH + col] = o * wv + xv * (1.f - wv) + sk;
            }
        }
    }
}

// ---------------------------------------------------------------------------
// weight = clip(sigmoid(LN(cw_pre)), .01, .99) in place, wave-per-row
// ---------------------------------------------------------------------------
__global__ __launch_bounds__(256) void weight_ln_kernel(
        float* __restrict__ wbuf, const float* __restrict__ g, const float* __restrict__ b) {
    int w = threadIdx.x >> 6, lane = threadIdx.x & 63;
    int row = blockIdx.x * 4 + w;
    float4 v = ((const float4*)(wbuf + row * CH))[lane];
    float s = v.x + v.y + v.z + v.w;
    float q = v.x * v.x + v.y * v.y + v.z * v.z + v.w * v.w;
    wave_reduce2(s, q);
    float m = s / (float)CH;
    float r = rsqrtf(q / (float)CH - m * m + 1e-5f);
    float4 g4 = ((const float4*)g)[lane];
    float4 b4 = ((const float4*)b)[lane];
    float4 o;
    o.x = fminf(fmaxf(sigmoid_f((v.x - m) * r * g4.x + b4.x), 0.01f), 0.99f);
    o.y = fminf(fmaxf(sigmoid_f((v.y - m) * r * g4.y + b4.y), 0.01f), 0.99f);
    o.z = fminf(fmaxf(sigmoid_f((v.z - m) * r * g4.z + b4.z), 0.01f), 0.99f);
    o.w = fminf(fmaxf(sigmoid_f((v.w - m) * r * g4.w + b4.w), 0.01f), 0.99f);
    ((float4*)(wbuf + row * CH))[lane] = o;
}

// ---------------------------------------------------------------------------
// depthwise causal conv (width 4) + bias + silu, BOTH directions in one pass.
// backward output written pre-flipped (reversed-sequence order).
// ---------------------------------------------------------------------------
__global__ __launch_bounds__(256) void conv_both_kernel(
        const float* __restrict__ xz,
        const float* __restrict__ wf, const float* __restrict__ wbf,
        const float* __restrict__ wb, const float* __restrict__ wbb,
        float* __restrict__ outf, float* __restrict__ outb) {
    int flat = blockIdx.x * 256 + threadIdx.x;   // over 4096*512
    int d = flat & (DINNER - 1);
    int row = flat >> 9;
    int l = row & (SEQ - 1);
    int b = row >> 10;
    float accf = wbf[d], accb = wbb[d];
#pragma unroll
    for (int k = 0; k < 4; ++k) {
        int jf = l - 3 + k;
        if (jf >= 0) accf += xz[(b * SEQ + jf) * (2 * DINNER) + d] * wf[d * 4 + k];
        int jb = l + 3 - k;
        if (jb < SEQ) accb += xz[(b * SEQ + jb) * (2 * DINNER) + d] * wb[d * 4 + k];
    }
    outf[flat] = silu_f(accf);
    outb[(b * SEQ + (SEQ - 1 - l)) * DINNER + d] = silu_f(accb);
}

// ---------------------------------------------------------------------------
// Chunked scan pass 1, both directions (blockIdx.z: dir*4+b).
// ---------------------------------------------------------------------------
__global__ __launch_bounds__(256) void scan_pass1_kernel(
        const float* __restrict__ df, const float* __restrict__ db,
        const float* __restrict__ uf, const float* __restrict__ ub,
        const float* __restrict__ xf, const float* __restrict__ xb,
        const float* __restrict__ Alf, const float* __restrict__ Alb,
        float* __restrict__ cAf, float* __restrict__ cAb,
        float* __restrict__ cHf, float* __restrict__ cHb) {
    int dir = blockIdx.z >> 2;
    int b = blockIdx.z & 3;
    const float* delta = dir ? db : df;
    const float* u     = dir ? ub : uf;
    const float* xdbl  = dir ? xb : xf;
    const float* A_log = dir ? Alb : Alf;
    float* chunkA = dir ? cAb : cAf;
    float* chunkH = dir ? cHb : cHf;

    int t = threadIdx.x;
    int n = t & 15;
    int dg = t >> 4;
    int d = blockIdx.x * 16 + dg;
    int c = blockIdx.y;
    float a = -__expf(A_log[d * DSTATE + n]);
    float P = 1.f, hp = 0.f;
    int base = b * SEQ + c * CHUNK;
    for (int s = 0; s < CHUNK; ++s) {
        int row = base + s;
        float dl = delta[row * DINNER + d];
        float ul = u[row * DINNER + d];
        float Bn = xdbl[row * 64 + DTRANK + n];
        float dA = __expf(dl * a);
        hp = dA * hp + dl * ul * Bn;
        P *= dA;
    }
    int idx = ((b * NCHUNK + c) * DINNER + d) * DSTATE + n;
    chunkA[idx] = P;
    chunkH[idx] = hp;
}

// ---------------------------------------------------------------------------
// Pass 2, both directions in one launch (65536 threads).
// ---------------------------------------------------------------------------
__global__ __launch_bounds__(256) void scan_pass2_kernel(
        const float* __restrict__ cAf, const float* __restrict__ cAb,
        float* __restrict__ cHf, float* __restrict__ cHb) {
    int tid = blockIdx.x * 256 + threadIdx.x;   // 0..65535
    int dir = tid >> 15;
    int rr = tid & 32767;
    int b = rr >> 13;
    int rem = rr & 8191;
    const float* chunkA = dir ? cAb : cAf;
    float* chunkH = dir ? cHb : cHf;
    float h = 0.f;
    for (int c = 0; c < NCHUNK; ++c) {
        int idx = (b * NCHUNK + c) * (DINNER * DSTATE) + rem;
        float Ac = chunkA[idx];
        float Hc = chunkH[idx];
        chunkH[idx] = h;
        h = Ac * h + Hc;
    }
}

// ---------------------------------------------------------------------------
// Pass 3, both directions (blockIdx.z: dir*4+b). Backward writes flipped.
// ---------------------------------------------------------------------------
__global__ __launch_bounds__(256) void scan_pass3_kernel(
        const float* __restrict__ df, const float* __restrict__ db,
        const float* __restrict__ uf, const float* __restrict__ ub,
        const float* __restrict__ xf, const float* __restrict__ xb,
        const float* __restrict__ Alf, const float* __restrict__ Alb,
        const float* __restrict__ Dvf, const float* __restrict__ Dvb,
        const float* __restrict__ hf, const float* __restrict__ hb,
        float* __restrict__ yf, float* __restrict__ yb) {
    int dir = blockIdx.z >> 2;
    int b = blockIdx.z & 3;
    const float* delta = dir ? db : df;
    const float* u     = dir ? ub : uf;
    const float* xdbl  = dir ? xb : xf;
    const float* A_log = dir ? Alb : Alf;
    const float* Dv    = dir ? Dvb : Dvf;
    const float* hin   = dir ? hb : hf;
    float* yout        = dir ? yb : yf;

    int t = threadIdx.x;
    int n = t & 15;
    int dg = t >> 4;
    int d = blockIdx.x * 16 + dg;
    int c = blockIdx.y;
    float a = -__expf(A_log[d * DSTATE + n]);
    float Dd = Dv[d];
    float h = hin[((b * NCHUNK + c) * DINNER + d) * DSTATE + n];
    int base = b * SEQ + c * CHUNK;
    for (int s = 0; s < CHUNK; ++s) {
        int row = base + s;
        float dl = delta[row * DINNER + d];
        float ul = u[row * DINNER + d];
        float Bn = xdbl[row * 64 + DTRANK + n];
        float Cn = xdbl[row * 64 + DTRANK + DSTATE + n];
        float dA = __expf(dl * a);
        h = dA * h + dl * ul * Bn;
        float yp = h * Cn;
        yp += __shfl_xor(yp, 8, 16);
        yp += __shfl_xor(yp, 4, 16);
        yp += __shfl_xor(yp, 2, 16);
        yp += __shfl_xor(yp, 1, 16);
        if (n == 0) {
            int lpos = c * CHUNK + s;
            int orow = b * SEQ + (dir ? (SEQ - 1 - lpos) : lpos);
            yout[orow * DINNER + d] = yp + Dd * ul;
        }
    }
}

// ---------------------------------------------------------------------------
// combine + mnorm, wave-per-row (512 floats = 2 float4 per lane)
// ---------------------------------------------------------------------------
__global__ __launch_bounds__(256) void combine_mnorm_kernel(
        const float* __restrict__ yf, const float* __restrict__ yb,
        const float* __restrict__ xz,
        const float* __restrict__ g, const float* __restrict__ b,
        float* __restrict__ yn) {
    int w = threadIdx.x >> 6, lane = threadIdx.x & 63;
    int row = blockIdx.x * 4 + w;
    const float4* yf4 = (const float4*)(yf + row * DINNER);
    const float4* yb4 = (const float4*)(yb + row * DINNER);
    const float4* z4 = (const float4*)(xz + row * (2 * DINNER) + DINNER);
    float4 va, vb;
    {
        float4 f0 = yf4[lane], b0 = yb4[lane], z0 = z4[lane];
        va.x = 0.5f * (f0.x + b0.x) * silu_f(z0.x);
        va.y = 0.5f * (f0.y + b0.y) * silu_f(z0.y);
        va.z = 0.5f * (f0.z + b0.z) * silu_f(z0.z);
        va.w = 0.5f * (f0.w + b0.w) * silu_f(z0.w);
        float4 f1 = yf4[lane + 64], b1 = yb4[lane + 64], z1 = z4[lane + 64];
        vb.x = 0.5f * (f1.x + b1.x) * silu_f(z1.x);
        vb.y = 0.5f * (f1.y + b1.y) * silu_f(z1.y);
        vb.z = 0.5f * (f1.z + b1.z) * silu_f(z1.z);
        vb.w = 0.5f * (f1.w + b1.w) * silu_f(z1.w);
    }
    float s = va.x + va.y + va.z + va.w + vb.x + vb.y + vb.z + vb.w;
    float q = va.x * va.x + va.y * va.y + va.z * va.z + va.w * va.w
            + vb.x * vb.x + vb.y * vb.y + vb.z * vb.z + vb.w * vb.w;
    wave_reduce2(s, q);
    float m = s / (float)DINNER;
    float r = rsqrtf(q / (float)DINNER - m * m + 1e-5f);
    float4 g0 = ((const float4*)g)[lane], b0 = ((const float4*)b)[lane];
    float4 g1 = ((const float4*)g)[lane + 64], b1 = ((const float4*)b)[lane + 64];
    float4 o0, o1;
    o0.x = (va.x - m) * r * g0.x + b0.x;
    o0.y = (va.y - m) * r * g0.y + b0.y;
    o0.z = (va.z - m) * r * g0.z + b0.z;
    o0.w = (va.w - m) * r * g0.w + b0.w;
    o1.x = (vb.x - m) * r * g1.x + b1.x;
    o1.y = (vb.y - m) * r * g1.y + b1.y;
    o1.z = (vb.z - m) * r * g1.z + b1.z;
    o1.w = (vb.w - m) * r * g1.w + b1.w;
    ((float4*)(yn + row * DINNER))[lane] = o0;
    ((float4*)(yn + row * DINNER))[lane + 64] = o1;
}

// ---------------------------------------------------------------------------
// plain LN over 512 (pnorm), wave-per-row
// ---------------------------------------------------------------------------
__global__ __launch_bounds__(256) void ln512_kernel(
        const float* __restrict__ in,
        const float* __restrict__ g, const float* __restrict__ b,
        float* __restrict__ out) {
    int w = threadIdx.x >> 6, lane = threadIdx.x & 63;
    int row = blockIdx.x * 4 + w;
    const float4* p = (const float4*)(in + row * DMODEL);
    float4 va = p[lane], vb = p[lane + 64];
    float s = va.x + va.y + va.z + va.w + vb.x + vb.y + vb.z + vb.w;
    float q = va.x * va.x + va.y * va.y + va.z * va.z + va.w * va.w
            + vb.x * vb.x + vb.y * vb.y + vb.z * vb.z + vb.w * vb.w;
    wave_reduce2(s, q);
    float m = s / (float)DMODEL;
    float r = rsqrtf(q / (float)DMODEL - m * m + 1e-5f);
    float4 g0 = ((const float4*)g)[lane], b0 = ((const float4*)b)[lane];
    float4 g1 = ((const float4*)g)[lane + 64], b1 = ((const float4*)b)[lane + 64];
    float4 o0, o1;
    o0.x = (va.x - m) * r * g0.x + b0.x;
    o0.y = (va.y - m) * r * g0.y + b0.y;
    o0.z = (va.z - m) * r * g0.z + b0.z;
    o0.w = (va.w - m) * r * g0.w + b0.w;
    o1.x = (vb.x - m) * r * g1.x + b1.x;
    o1.y = (vb.y - m) * r * g1.y + b1.y;
    o1.z = (vb.z - m) * r * g1.z + b1.z;
    o1.w = (vb.w - m) * r * g1.w + b1.w;
    ((float4*)(out + row * DMODEL))[lane] = o0;
    ((float4*)(out + row * DMODEL))[lane + 64] = o1;
}

extern "C" void kernel_launch(void* const* d_in, const int* in_sizes, int n_in,
                              void* d_out, int out_size, void* d_ws, size_t ws_size,
                              hipStream_t stream) {
    (void)in_sizes; (void)n_in; (void)out_size; (void)ws_size;
    const float* input0    = (const float*)d_in[0];
    const float* input1    = (const float*)d_in[1];
    const float* norm0_g   = (const float*)d_in[2];
    const float* norm0_b   = (const float*)d_in[3];
    const float* norm1_g   = (const float*)d_in[4];
    const float* norm1_b   = (const float*)d_in[5];
    const float* in_proj_w = (const float*)d_in[6];
    const float* convf_w   = (const float*)d_in[7];
    const float* convf_b   = (const float*)d_in[8];
    const float* xprojf_w  = (const float*)d_in[9];
    const float* dtf_w     = (const float*)d_in[10];
    const float* dtf_b     = (const float*)d_in[11];
    const float* A_log_f   = (const float*)d_in[12];
    const float* D_f       = (const float*)d_in[13];
    const float* convb_w   = (const float*)d_in[14];
    const float* convb_b   = (const float*)d_in[15];
    const float* xprojb_w  = (const float*)d_in[16];
    const float* dtb_w     = (const float*)d_in[17];
    const float* dtb_b     = (const float*)d_in[18];
    const float* A_log_b   = (const float*)d_in[19];
    const float* D_b       = (const float*)d_in[20];
    const float* mnorm_g   = (const float*)d_in[21];
    const float* mnorm_b   = (const float*)d_in[22];
    const float* outproj_w = (const float*)d_in[23];
    const float* pnorm_g   = (const float*)d_in[24];
    const float* pnorm_b   = (const float*)d_in[25];
    const float* projback_w= (const float*)d_in[26];
    const float* projback_b= (const float*)d_in[27];
    const float* cw_w      = (const float*)d_in[28];
    const float* cw_b      = (const float*)d_in[29];
    const float* cwln_g    = (const float*)d_in[30];
    const float* cwln_b    = (const float*)d_in[31];

    float* ws = (float*)d_ws;
    float* x0n      = ws;                       // 1,048,576
    float* combined = x0n + 1048576;            // 2,097,152
    float* xz       = combined + 2097152;       // 4,194,304
    float* weight   = xz + 4194304;             // 1,048,576
    float* xdbl_f   = weight + 1048576;         //   262,144
    float* xdbl_b   = xdbl_f + 262144;          //   262,144
    float* xconv_f  = xdbl_b + 262144;          // 2,097,152
    float* xconv_b  = xconv_f + 2097152;        // 2,097,152
    float* delta_f  = xconv_b + 2097152;        // 2,097,152
    float* delta_b  = delta_f + 2097152;        // 2,097,152
    float* y_f      = delta_b + 2097152;        // 2,097,152
    float* y_b      = y_f + 2097152;            // 2,097,152
    // combined is dead between the cw GEMM and step 9 -> alias chunk state:
    float* chunkA_f = combined;
    float* chunkH_f = combined + 524288;
    float* chunkA_b = combined + 1048576;
    float* chunkH_b = combined + 1572864;
    float* yn  = combined;   // written after scans complete
    float* o1  = xconv_f;    // dead after scan
    float* on1 = xconv_b;    // dead after scan

    // 1. LN of both inputs -> x0n, combined
    ln01_kernel<<<NROWS / 4, 256, 0, stream>>>(input0, input1, norm0_g, norm0_b,
                                               norm1_g, norm1_b, x0n, combined);

    // 2. xz = combined @ in_proj_w^T
    gemm_mfma_kernel<0><<<dim3(16, 64, 1), 256, 0, stream>>>(
        combined, combined, DMODEL, in_proj_w, in_proj_w, DMODEL,
        xz, xz, 2 * DINNER, DMODEL, nullptr, nullptr);

    // 3. cw_pre = combined @ cw_w^T + cw_b
    gemm_mfma_kernel<0><<<dim3(4, 64, 1), 256, 0, stream>>>(
        combined, combined, DMODEL, cw_w, cw_w, DMODEL,
        weight, weight, CH, DMODEL, cw_b, cw_b);

    // 4. weight = clip(sigmoid(LN(cw_pre)))
    weight_ln_kernel<<<NROWS / 4, 256, 0, stream>>>(weight, cwln_g, cwln_b);

    // 5. conv + silu, both directions in one pass over xz
    conv_both_kernel<<<NROWS * DINNER / 256, 256, 0, stream>>>(
        xz, convf_w, convf_b, convb_w, convb_b, xconv_f, xconv_b);

    // 6. x_dbl = xconv @ xproj_w^T  (batched f/b)
    gemm_mfma_kernel<0><<<dim3(1, 64, 2), 256, 0, stream>>>(
        xconv_f, xconv_b, DINNER, xprojf_w, xprojb_w, DINNER,
        xdbl_f, xdbl_b, 64, DINNER, nullptr, nullptr);

    // 7. delta = softplus(x_dbl[:, :32] @ dt_w^T + dt_b)  (batched f/b)
    gemm_mfma_kernel<1><<<dim3(8, 64, 2), 256, 0, stream>>>(
        xdbl_f, xdbl_b, 64, dtf_w, dtb_w, DTRANK,
        delta_f, delta_b, DINNER, DTRANK, dtf_b, dtb_b);

    // 8. chunked scan (pass1/2/3, both directions per launch)
    scan_pass1_kernel<<<dim3(32, NCHUNK, 2 * BDIM), 256, 0, stream>>>(
        delta_f, delta_b, xconv_f, xconv_b, xdbl_f, xdbl_b, A_log_f, A_log_b,
        chunkA_f, chunkA_b, chunkH_f, chunkH_b);
    scan_pass2_kernel<<<256, 256, 0, stream>>>(chunkA_f, chunkA_b, chunkH_f, chunkH_b);
    scan_pass3_kernel<<<dim3(32, NCHUNK, 2 * BDIM), 256, 0, stream>>>(
        delta_f, delta_b, xconv_f, xconv_b, xdbl_f, xdbl_b, A_log_f, A_log_b,
        D_f, D_b, chunkH_f, chunkH_b, y_f, y_b);

    // 9. combine + mnorm LN -> yn
    combine_mnorm_kernel<<<NROWS / 4, 256, 0, stream>>>(y_f, y_b, xz, mnorm_g, mnorm_b, yn);

    // 10. o1 = yn @ outproj_w^T
    gemm_mfma_kernel<0><<<dim3(8, 64, 1), 256, 0, stream>>>(
        yn, yn, DINNER, outproj_w, outproj_w, DINNER,
        o1, o1, DMODEL, DINNER, nullptr, nullptr);

    // 11. pnorm LN -> on1
    ln512_kernel<<<NROWS / 4, 256, 0, stream>>>(o1, pnorm_g, pnorm_b, on1);

    // 12+13. projback GEMM fused with final blend + skip -> fp32 out
    gemm_projback_final_kernel<<<dim3(4, 64, 1), 256, 0, stream>>>(
        on1, DMODEL, projback_w, DMODEL, DMODEL, projback_b,
        weight, x0n, input0, (float*)d_out);
}

// Round 6
// 317.573 us; speedup vs baseline: 4.5037x; 1.1745x over previous
//
#include <hip/hip_runtime.h>

#define BDIM 4
#define SEQ 1024
#define CH 256
#define DMODEL 512
#define DINNER 512
#define DSTATE 16
#define DTRANK 32
#define NROWS (BDIM * SEQ)   // 4096
#define NCHUNK 32
#define CHUNK (SEQ / NCHUNK) // 32

typedef unsigned short ushort_t;

__device__ __forceinline__ float nan2num(float x) {
    if (isnan(x)) return 0.f;
    if (isinf(x)) return x > 0.f ? 1.f : -1.f;
    return x;
}

__device__ __forceinline__ float silu_f(float x) { return x / (1.f + __expf(-x)); }
__device__ __forceinline__ float sigmoid_f(float x) { return 1.f / (1.f + __expf(-x)); }
__device__ __forceinline__ float softplus_f(float x) {
    return x > 20.f ? x : log1pf(__expf(x));
}

// fp32 -> bf16 round-to-nearest-even
__device__ __forceinline__ ushort_t f2bf(float x) {
    union { float f; unsigned u; } v; v.f = x;
    unsigned r = v.u + 0x7fff + ((v.u >> 16) & 1);
    return (ushort_t)(r >> 16);
}

using bf16x8 = __attribute__((ext_vector_type(8))) __bf16;
using f32x4  = __attribute__((ext_vector_type(4))) float;

// wave-wide (64-lane) reduction of (s,q)
__device__ __forceinline__ void wave_reduce2(float& s, float& q) {
#pragma unroll
    for (int m = 32; m > 0; m >>= 1) {
        s += __shfl_xor(s, m);
        q += __shfl_xor(q, m);
    }
}

// ---------------------------------------------------------------------------
// ln01: wave-per-row LN of i0 and i1 -> x0n, combined
// ---------------------------------------------------------------------------
__global__ __launch_bounds__(256) void ln01_kernel(
        const float* __restrict__ i0, const float* __restrict__ i1,
        const float* __restrict__ g0, const float* __restrict__ b0,
        const float* __restrict__ g1, const float* __restrict__ b1,
        float* __restrict__ x0n, float* __restrict__ combined) {
    int w = threadIdx.x >> 6, lane = threadIdx.x & 63;
    int row = blockIdx.x * 4 + w;

    float4 v = ((const float4*)(i0 + row * CH))[lane];
    v.x = nan2num(v.x); v.y = nan2num(v.y); v.z = nan2num(v.z); v.w = nan2num(v.w);
    float s = v.x + v.y + v.z + v.w;
    float q = v.x * v.x + v.y * v.y + v.z * v.z + v.w * v.w;
    wave_reduce2(s, q);
    float m = s / (float)CH;
    float r = rsqrtf(q / (float)CH - m * m + 1e-5f);
    float4 g = ((const float4*)g0)[lane];
    float4 bb = ((const float4*)b0)[lane];
    float4 o;
    o.x = (v.x - m) * r * g.x + bb.x;
    o.y = (v.y - m) * r * g.y + bb.y;
    o.z = (v.z - m) * r * g.z + bb.z;
    o.w = (v.w - m) * r * g.w + bb.w;
    ((float4*)(x0n + row * CH))[lane] = o;
    ((float4*)(combined + row * DMODEL))[lane] = o;

    v = ((const float4*)(i1 + row * CH))[lane];
    v.x = nan2num(v.x); v.y = nan2num(v.y); v.z = nan2num(v.z); v.w = nan2num(v.w);
    s = v.x + v.y + v.z + v.w;
    q = v.x * v.x + v.y * v.y + v.z * v.z + v.w * v.w;
    wave_reduce2(s, q);
    m = s / (float)CH;
    r = rsqrtf(q / (float)CH - m * m + 1e-5f);
    g = ((const float4*)g1)[lane];
    bb = ((const float4*)b1)[lane];
    o.x = (v.x - m) * r * g.x + bb.x;
    o.y = (v.y - m) * r * g.y + bb.y;
    o.z = (v.z - m) * r * g.z + bb.z;
    o.w = (v.w - m) * r * g.w + bb.w;
    ((float4*)(combined + row * DMODEL + CH))[lane] = o;
}

// ---------------------------------------------------------------------------
// bf16-MFMA GEMM (NT), dual-batch via blockIdx.z.
// ---------------------------------------------------------------------------
template<int ACT>
__global__ __launch_bounds__(256) void gemm_mfma_kernel(
        const float* __restrict__ A0, const float* __restrict__ A1, int lda,
        const float* __restrict__ W0, const float* __restrict__ W1, int ldw,
        float* __restrict__ C0, float* __restrict__ C1, int ldc,
        int K, const float* __restrict__ bias0, const float* __restrict__ bias1) {
    const float* A = blockIdx.z ? A1 : A0;
    const float* W = blockIdx.z ? W1 : W0;
    float* C = blockIdx.z ? C1 : C0;
    const float* bias = blockIdx.z ? bias1 : bias0;

    __shared__ ushort_t As[64][40];
    __shared__ ushort_t Ws[64][40];
    const int t = threadIdx.x;
    const int m0 = blockIdx.y * 64;
    const int n0 = blockIdx.x * 64;
    const int w = t >> 6;
    const int lane = t & 63;
    const int lane16 = lane & 15;
    const int quad = lane >> 4;
    const int wr = (w >> 1) * 32;
    const int wc = (w & 1) * 32;
    const int srow = t >> 2;
    const int sc8 = (t & 3) * 8;

    f32x4 acc[2][2] = {};

    for (int k0 = 0; k0 < K; k0 += 32) {
        float4 a0 = *(const float4*)(A + (m0 + srow) * lda + k0 + sc8);
        float4 a1 = *(const float4*)(A + (m0 + srow) * lda + k0 + sc8 + 4);
        float4 w0 = *(const float4*)(W + (n0 + srow) * ldw + k0 + sc8);
        float4 w1 = *(const float4*)(W + (n0 + srow) * ldw + k0 + sc8 + 4);
        *(ushort4*)&As[srow][sc8]     = make_ushort4(f2bf(a0.x), f2bf(a0.y), f2bf(a0.z), f2bf(a0.w));
        *(ushort4*)&As[srow][sc8 + 4] = make_ushort4(f2bf(a1.x), f2bf(a1.y), f2bf(a1.z), f2bf(a1.w));
        *(ushort4*)&Ws[srow][sc8]     = make_ushort4(f2bf(w0.x), f2bf(w0.y), f2bf(w0.z), f2bf(w0.w));
        *(ushort4*)&Ws[srow][sc8 + 4] = make_ushort4(f2bf(w1.x), f2bf(w1.y), f2bf(w1.z), f2bf(w1.w));
        __syncthreads();

        bf16x8 af[2], bfr[2];
#pragma unroll
        for (int i = 0; i < 2; ++i) {
            af[i]  = *(bf16x8*)&As[wr + i * 16 + lane16][quad * 8];
            bfr[i] = *(bf16x8*)&Ws[wc + i * 16 + lane16][quad * 8];
        }
#pragma unroll
        for (int i = 0; i < 2; ++i)
#pragma unroll
            for (int j = 0; j < 2; ++j)
                acc[i][j] = __builtin_amdgcn_mfma_f32_16x16x32_bf16(af[i], bfr[j], acc[i][j], 0, 0, 0);
        __syncthreads();
    }

#pragma unroll
    for (int j = 0; j < 2; ++j) {
        int col = n0 + wc + j * 16 + lane16;
        float bv = bias ? bias[col] : 0.f;
#pragma unroll
        for (int i = 0; i < 2; ++i) {
#pragma unroll
            for (int r = 0; r < 4; ++r) {
                int row = m0 + wr + i * 16 + quad * 4 + r;
                float c = acc[i][j][r] + bv;
                if (ACT == 1) c = softplus_f(c);
                C[row * ldc + col] = c;
            }
        }
    }
}

// ---------------------------------------------------------------------------
// projback GEMM + final blend fused
// ---------------------------------------------------------------------------
__global__ __launch_bounds__(256) void gemm_projback_final_kernel(
        const float* __restrict__ A, int lda,
        const float* __restrict__ W, int ldw,
        int K, const float* __restrict__ bias,
        const float* __restrict__ wgt, const float* __restrict__ x0n,
        const float* __restrict__ i0, float* __restrict__ out) {
    __shared__ ushort_t As[64][40];
    __shared__ ushort_t Ws[64][40];
    const int t = threadIdx.x;
    const int m0 = blockIdx.y * 64;
    const int n0 = blockIdx.x * 64;
    const int w = t >> 6;
    const int lane = t & 63;
    const int lane16 = lane & 15;
    const int quad = lane >> 4;
    const int wr = (w >> 1) * 32;
    const int wc = (w & 1) * 32;
    const int srow = t >> 2;
    const int sc8 = (t & 3) * 8;

    f32x4 acc[2][2] = {};

    for (int k0 = 0; k0 < K; k0 += 32) {
        float4 a0 = *(const float4*)(A + (m0 + srow) * lda + k0 + sc8);
        float4 a1 = *(const float4*)(A + (m0 + srow) * lda + k0 + sc8 + 4);
        float4 w0 = *(const float4*)(W + (n0 + srow) * ldw + k0 + sc8);
        float4 w1 = *(const float4*)(W + (n0 + srow) * ldw + k0 + sc8 + 4);
        *(ushort4*)&As[srow][sc8]     = make_ushort4(f2bf(a0.x), f2bf(a0.y), f2bf(a0.z), f2bf(a0.w));
        *(ushort4*)&As[srow][sc8 + 4] = make_ushort4(f2bf(a1.x), f2bf(a1.y), f2bf(a1.z), f2bf(a1.w));
        *(ushort4*)&Ws[srow][sc8]     = make_ushort4(f2bf(w0.x), f2bf(w0.y), f2bf(w0.z), f2bf(w0.w));
        *(ushort4*)&Ws[srow][sc8 + 4] = make_ushort4(f2bf(w1.x), f2bf(w1.y), f2bf(w1.z), f2bf(w1.w));
        __syncthreads();

        bf16x8 af[2], bfr[2];
#pragma unroll
        for (int i = 0; i < 2; ++i) {
            af[i]  = *(bf16x8*)&As[wr + i * 16 + lane16][quad * 8];
            bfr[i] = *(bf16x8*)&Ws[wc + i * 16 + lane16][quad * 8];
        }
#pragma unroll
        for (int i = 0; i < 2; ++i)
#pragma unroll
            for (int j = 0; j < 2; ++j)
                acc[i][j] = __builtin_amdgcn_mfma_f32_16x16x32_bf16(af[i], bfr[j], acc[i][j], 0, 0, 0);
        __syncthreads();
    }

#pragma unroll
    for (int j = 0; j < 2; ++j) {
        int col = n0 + wc + j * 16 + lane16;
        float bv = bias[col];
#pragma unroll
        for (int i = 0; i < 2; ++i) {
#pragma unroll
            for (int r = 0; r < 4; ++r) {
                int row = m0 + wr + i * 16 + quad * 4 + r;
                float o = nan2num(acc[i][j][r] + bv);
                float wv = wgt[row * CH + col];
                float xv = x0n[row * CH + col];
                float sk = nan2num(i0[row * CH + col]);
                out[row * CH + col] = o * wv + xv * (1.f - wv) + sk;
            }
        }
    }
}

// ---------------------------------------------------------------------------
// weight = clip(sigmoid(LN(cw_pre)), .01, .99) in place, wave-per-row
// ---------------------------------------------------------------------------
__global__ __launch_bounds__(256) void weight_ln_kernel(
        float* __restrict__ wbuf, const float* __restrict__ g, const float* __restrict__ b) {
    int w = threadIdx.x >> 6, lane = threadIdx.x & 63;
    int row = blockIdx.x * 4 + w;
    float4 v = ((const float4*)(wbuf + row * CH))[lane];
    float s = v.x + v.y + v.z + v.w;
    float q = v.x * v.x + v.y * v.y + v.z * v.z + v.w * v.w;
    wave_reduce2(s, q);
    float m = s / (float)CH;
    float r = rsqrtf(q / (float)CH - m * m + 1e-5f);
    float4 g4 = ((const float4*)g)[lane];
    float4 b4 = ((const float4*)b)[lane];
    float4 o;
    o.x = fminf(fmaxf(sigmoid_f((v.x - m) * r * g4.x + b4.x), 0.01f), 0.99f);
    o.y = fminf(fmaxf(sigmoid_f((v.y - m) * r * g4.y + b4.y), 0.01f), 0.99f);
    o.z = fminf(fmaxf(sigmoid_f((v.z - m) * r * g4.z + b4.z), 0.01f), 0.99f);
    o.w = fminf(fmaxf(sigmoid_f((v.w - m) * r * g4.w + b4.w), 0.01f), 0.99f);
    ((float4*)(wbuf + row * CH))[lane] = o;
}

// ---------------------------------------------------------------------------
// depthwise causal conv (width 4) + bias + silu, BOTH directions in one pass
// ---------------------------------------------------------------------------
__global__ __launch_bounds__(256) void conv_both_kernel(
        const float* __restrict__ xz,
        const float* __restrict__ wf, const float* __restrict__ wbf,
        const float* __restrict__ wb, const float* __restrict__ wbb,
        float* __restrict__ outf, float* __restrict__ outb) {
    int flat = blockIdx.x * 256 + threadIdx.x;   // over 4096*512
    int d = flat & (DINNER - 1);
    int row = flat >> 9;
    int l = row & (SEQ - 1);
    int b = row >> 10;
    float accf = wbf[d], accb = wbb[d];
#pragma unroll
    for (int k = 0; k < 4; ++k) {
        int jf = l - 3 + k;
        if (jf >= 0) accf += xz[(b * SEQ + jf) * (2 * DINNER) + d] * wf[d * 4 + k];
        int jb = l + 3 - k;
        if (jb < SEQ) accb += xz[(b * SEQ + jb) * (2 * DINNER) + d] * wb[d * 4 + k];
    }
    outf[flat] = silu_f(accf);
    outb[(b * SEQ + (SEQ - 1 - l)) * DINNER + d] = silu_f(accb);
}

// ---------------------------------------------------------------------------
// Scan pass 1, thread-per-d, 16 states in registers.
// grid = (DINNER/256, NCHUNK, 2*BDIM); block = 256.
// Per chunk: P_n = exp(a_n * sum(dl)), hp_n = chunk-local scan from 0.
// ---------------------------------------------------------------------------
__global__ __launch_bounds__(256) void scan_pass1_kernel(
        const float* __restrict__ df, const float* __restrict__ db,
        const float* __restrict__ uf, const float* __restrict__ ub,
        const float* __restrict__ xf, const float* __restrict__ xb,
        const float* __restrict__ Alf, const float* __restrict__ Alb,
        float* __restrict__ cAf, float* __restrict__ cAb,
        float* __restrict__ cHf, float* __restrict__ cHb) {
    const int dir = blockIdx.z >> 2;
    const int b = blockIdx.z & 3;
    const float* delta = dir ? db : df;
    const float* u     = dir ? ub : uf;
    const float* xdbl  = dir ? xb : xf;
    const float* A_log = dir ? Alb : Alf;
    float* chunkA = dir ? cAb : cAf;
    float* chunkH = dir ? cHb : cHf;

    const int c = blockIdx.y;
    const int d = blockIdx.x * 256 + threadIdx.x;
    const int base = b * SEQ + c * CHUNK;

    // stage B columns (32..47) of the chunk into LDS: wave-uniform per l
    __shared__ float sB[CHUNK][16];
    {
        int t = threadIdx.x;
        if (t < CHUNK * 4) {
            int row = t >> 2, f4 = t & 3;
            float4 v = *(const float4*)(xdbl + (base + row) * 64 + DTRANK + f4 * 4);
            *(float4*)&sB[row][f4 * 4] = v;
        }
    }
    __syncthreads();

    float a[DSTATE];
#pragma unroll
    for (int n = 0; n < DSTATE; n += 4) {
        float4 al = *(const float4*)(A_log + d * DSTATE + n);
        a[n] = -__expf(al.x); a[n + 1] = -__expf(al.y);
        a[n + 2] = -__expf(al.z); a[n + 3] = -__expf(al.w);
    }
    float h[DSTATE];
#pragma unroll
    for (int n = 0; n < DSTATE; ++n) h[n] = 0.f;

    float sumdl = 0.f;
    float dl = delta[base * DINNER + d];
    float ul = u[base * DINNER + d];
    for (int s = 0; s < CHUNK; ++s) {
        int nrow = base + ((s + 1 < CHUNK) ? s + 1 : s);
        float dln = delta[nrow * DINNER + d];
        float uln = u[nrow * DINNER + d];
        float dlul = dl * ul;
        sumdl += dl;
#pragma unroll
        for (int g = 0; g < 4; ++g) {
            float4 B4 = *(const float4*)&sB[s][g * 4];
            float dA0 = __expf(dl * a[g * 4 + 0]);
            float dA1 = __expf(dl * a[g * 4 + 1]);
            float dA2 = __expf(dl * a[g * 4 + 2]);
            float dA3 = __expf(dl * a[g * 4 + 3]);
            h[g * 4 + 0] = dA0 * h[g * 4 + 0] + dlul * B4.x;
            h[g * 4 + 1] = dA1 * h[g * 4 + 1] + dlul * B4.y;
            h[g * 4 + 2] = dA2 * h[g * 4 + 2] + dlul * B4.z;
            h[g * 4 + 3] = dA3 * h[g * 4 + 3] + dlul * B4.w;
        }
        dl = dln; ul = uln;
    }

    int idx = ((b * NCHUNK + c) * DINNER + d) * DSTATE;
#pragma unroll
    for (int n = 0; n < DSTATE; n += 4) {
        float4 P4 = make_float4(__expf(a[n] * sumdl), __expf(a[n + 1] * sumdl),
                                __expf(a[n + 2] * sumdl), __expf(a[n + 3] * sumdl));
        *(float4*)(chunkA + idx + n) = P4;
        *(float4*)(chunkH + idx + n) = make_float4(h[n], h[n + 1], h[n + 2], h[n + 3]);
    }
}

// ---------------------------------------------------------------------------
// Pass 2: sequential combine over chunks (in place -> incoming h per chunk)
// ---------------------------------------------------------------------------
__global__ __launch_bounds__(256) void scan_pass2_kernel(
        const float* __restrict__ cAf, const float* __restrict__ cAb,
        float* __restrict__ cHf, float* __restrict__ cHb) {
    int tid = blockIdx.x * 256 + threadIdx.x;   // 0..65535
    int dir = tid >> 15;
    int rr = tid & 32767;
    int b = rr >> 13;
    int rem = rr & 8191;
    const float* chunkA = dir ? cAb : cAf;
    float* chunkH = dir ? cHb : cHf;
    float h = 0.f;
    for (int c = 0; c < NCHUNK; ++c) {
        int idx = (b * NCHUNK + c) * (DINNER * DSTATE) + rem;
        float Ac = chunkA[idx];
        float Hc = chunkH[idx];
        chunkH[idx] = h;
        h = Ac * h + Hc;
    }
}

// ---------------------------------------------------------------------------
// Pass 3: thread-per-d re-scan seeded with incoming h, emit y.
// ---------------------------------------------------------------------------
__global__ __launch_bounds__(256) void scan_pass3_kernel(
        const float* __restrict__ df, const float* __restrict__ db,
        const float* __restrict__ uf, const float* __restrict__ ub,
        const float* __restrict__ xf, const float* __restrict__ xb,
        const float* __restrict__ Alf, const float* __restrict__ Alb,
        const float* __restrict__ Dvf, const float* __restrict__ Dvb,
        const float* __restrict__ hfb, const float* __restrict__ hbb,
        float* __restrict__ yfo, float* __restrict__ ybo) {
    const int dir = blockIdx.z >> 2;
    const int b = blockIdx.z & 3;
    const float* delta = dir ? db : df;
    const float* u     = dir ? ub : uf;
    const float* xdbl  = dir ? xb : xf;
    const float* A_log = dir ? Alb : Alf;
    const float* Dv    = dir ? Dvb : Dvf;
    const float* hin   = dir ? hbb : hfb;
    float* yout        = dir ? ybo : yfo;

    const int c = blockIdx.y;
    const int d = blockIdx.x * 256 + threadIdx.x;
    const int base = b * SEQ + c * CHUNK;

    // stage B (cols 32..47) and C (cols 48..63) of the chunk into LDS
    __shared__ float sBC[CHUNK][32];
    {
        int t = threadIdx.x;                      // 256 = CHUNK*8
        int row = t >> 3, f4 = t & 7;
        float4 v = *(const float4*)(xdbl + (base + row) * 64 + DTRANK + f4 * 4);
        *(float4*)&sBC[row][f4 * 4] = v;
    }
    __syncthreads();

    float a[DSTATE];
#pragma unroll
    for (int n = 0; n < DSTATE; n += 4) {
        float4 al = *(const float4*)(A_log + d * DSTATE + n);
        a[n] = -__expf(al.x); a[n + 1] = -__expf(al.y);
        a[n + 2] = -__expf(al.z); a[n + 3] = -__expf(al.w);
    }
    float h[DSTATE];
    {
        int idx = ((b * NCHUNK + c) * DINNER + d) * DSTATE;
#pragma unroll
        for (int n = 0; n < DSTATE; n += 4) {
            float4 h4 = *(const float4*)(hin + idx + n);
            h[n] = h4.x; h[n + 1] = h4.y; h[n + 2] = h4.z; h[n + 3] = h4.w;
        }
    }
    const float Dd = Dv[d];

    float dl = delta[base * DINNER + d];
    float ul = u[base * DINNER + d];
    for (int s = 0; s < CHUNK; ++s) {
        int nrow = base + ((s + 1 < CHUNK) ? s + 1 : s);
        float dln = delta[nrow * DINNER + d];
        float uln = u[nrow * DINNER + d];
        float dlul = dl * ul;
        float y = 0.f;
#pragma unroll
        for (int g = 0; g < 4; ++g) {
            float4 B4 = *(const float4*)&sBC[s][g * 4];
            float4 C4 = *(const float4*)&sBC[s][16 + g * 4];
            float dA0 = __expf(dl * a[g * 4 + 0]);
            float dA1 = __expf(dl * a[g * 4 + 1]);
            float dA2 = __expf(dl * a[g * 4 + 2]);
            float dA3 = __expf(dl * a[g * 4 + 3]);
            h[g * 4 + 0] = dA0 * h[g * 4 + 0] + dlul * B4.x;
            h[g * 4 + 1] = dA1 * h[g * 4 + 1] + dlul * B4.y;
            h[g * 4 + 2] = dA2 * h[g * 4 + 2] + dlul * B4.z;
            h[g * 4 + 3] = dA3 * h[g * 4 + 3] + dlul * B4.w;
            y += h[g * 4 + 0] * C4.x + h[g * 4 + 1] * C4.y
               + h[g * 4 + 2] * C4.z + h[g * 4 + 3] * C4.w;
        }
        int lpos = c * CHUNK + s;
        int orow = b * SEQ + (dir ? (SEQ - 1 - lpos) : lpos);
        yout[orow * DINNER + d] = y + Dd * ul;
        dl = dln; ul = uln;
    }
}

// ---------------------------------------------------------------------------
// combine + mnorm, wave-per-row
// ---------------------------------------------------------------------------
__global__ __launch_bounds__(256) void combine_mnorm_kernel(
        const float* __restrict__ yf, const float* __restrict__ yb,
        const float* __restrict__ xz,
        const float* __restrict__ g, const float* __restrict__ b,
        float* __restrict__ yn) {
    int w = threadIdx.x >> 6, lane = threadIdx.x & 63;
    int row = blockIdx.x * 4 + w;
    const float4* yf4 = (const float4*)(yf + row * DINNER);
    const float4* yb4 = (const float4*)(yb + row * DINNER);
    const float4* z4 = (const float4*)(xz + row * (2 * DINNER) + DINNER);
    float4 va, vb;
    {
        float4 f0 = yf4[lane], b0 = yb4[lane], z0 = z4[lane];
        va.x = 0.5f * (f0.x + b0.x) * silu_f(z0.x);
        va.y = 0.5f * (f0.y + b0.y) * silu_f(z0.y);
        va.z = 0.5f * (f0.z + b0.z) * silu_f(z0.z);
        va.w = 0.5f * (f0.w + b0.w) * silu_f(z0.w);
        float4 f1 = yf4[lane + 64], b1 = yb4[lane + 64], z1 = z4[lane + 64];
        vb.x = 0.5f * (f1.x + b1.x) * silu_f(z1.x);
        vb.y = 0.5f * (f1.y + b1.y) * silu_f(z1.y);
        vb.z = 0.5f * (f1.z + b1.z) * silu_f(z1.z);
        vb.w = 0.5f * (f1.w + b1.w) * silu_f(z1.w);
    }
    float s = va.x + va.y + va.z + va.w + vb.x + vb.y + vb.z + vb.w;
    float q = va.x * va.x + va.y * va.y + va.z * va.z + va.w * va.w
            + vb.x * vb.x + vb.y * vb.y + vb.z * vb.z + vb.w * vb.w;
    wave_reduce2(s, q);
    float m = s / (float)DINNER;
    float r = rsqrtf(q / (float)DINNER - m * m + 1e-5f);
    float4 g0 = ((const float4*)g)[lane], b0 = ((const float4*)b)[lane];
    float4 g1 = ((const float4*)g)[lane + 64], b1 = ((const float4*)b)[lane + 64];
    float4 o0, o1;
    o0.x = (va.x - m) * r * g0.x + b0.x;
    o0.y = (va.y - m) * r * g0.y + b0.y;
    o0.z = (va.z - m) * r * g0.z + b0.z;
    o0.w = (va.w - m) * r * g0.w + b0.w;
    o1.x = (vb.x - m) * r * g1.x + b1.x;
    o1.y = (vb.y - m) * r * g1.y + b1.y;
    o1.z = (vb.z - m) * r * g1.z + b1.z;
    o1.w = (vb.w - m) * r * g1.w + b1.w;
    ((float4*)(yn + row * DINNER))[lane] = o0;
    ((float4*)(yn + row * DINNER))[lane + 64] = o1;
}

// ---------------------------------------------------------------------------
// plain LN over 512 (pnorm), wave-per-row
// ---------------------------------------------------------------------------
__global__ __launch_bounds__(256) void ln512_kernel(
        const float* __restrict__ in,
        const float* __restrict__ g, const float* __restrict__ b,
        float* __restrict__ out) {
    int w = threadIdx.x >> 6, lane = threadIdx.x & 63;
    int row = blockIdx.x * 4 + w;
    const float4* p = (const float4*)(in + row * DMODEL);
    float4 va = p[lane], vb = p[lane + 64];
    float s = va.x + va.y + va.z + va.w + vb.x + vb.y + vb.z + vb.w;
    float q = va.x * va.x + va.y * va.y + va.z * va.z + va.w * va.w
            + vb.x * vb.x + vb.y * vb.y + vb.z * vb.z + vb.w * vb.w;
    wave_reduce2(s, q);
    float m = s / (float)DMODEL;
    float r = rsqrtf(q / (float)DMODEL - m * m + 1e-5f);
    float4 g0 = ((const float4*)g)[lane], b0 = ((const float4*)b)[lane];
    float4 g1 = ((const float4*)g)[lane + 64], b1 = ((const float4*)b)[lane + 64];
    float4 o0, o1;
    o0.x = (va.x - m) * r * g0.x + b0.x;
    o0.y = (va.y - m) * r * g0.y + b0.y;
    o0.z = (va.z - m) * r * g0.z + b0.z;
    o0.w = (va.w - m) * r * g0.w + b0.w;
    o1.x = (vb.x - m) * r * g1.x + b1.x;
    o1.y = (vb.y - m) * r * g1.y + b1.y;
    o1.z = (vb.z - m) * r * g1.z + b1.z;
    o1.w = (vb.w - m) * r * g1.w + b1.w;
    ((float4*)(out + row * DMODEL))[lane] = o0;
    ((float4*)(out + row * DMODEL))[lane + 64] = o1;
}

extern "C" void kernel_launch(void* const* d_in, const int* in_sizes, int n_in,
                              void* d_out, int out_size, void* d_ws, size_t ws_size,
                              hipStream_t stream) {
    (void)in_sizes; (void)n_in; (void)out_size; (void)ws_size;
    const float* input0    = (const float*)d_in[0];
    const float* input1    = (const float*)d_in[1];
    const float* norm0_g   = (const float*)d_in[2];
    const float* norm0_b   = (const float*)d_in[3];
    const float* norm1_g   = (const float*)d_in[4];
    const float* norm1_b   = (const float*)d_in[5];
    const float* in_proj_w = (const float*)d_in[6];
    const float* convf_w   = (const float*)d_in[7];
    const float* convf_b   = (const float*)d_in[8];
    const float* xprojf_w  = (const float*)d_in[9];
    const float* dtf_w     = (const float*)d_in[10];
    const float* dtf_b     = (const float*)d_in[11];
    const float* A_log_f   = (const float*)d_in[12];
    const float* D_f       = (const float*)d_in[13];
    const float* convb_w   = (const float*)d_in[14];
    const float* convb_b   = (const float*)d_in[15];
    const float* xprojb_w  = (const float*)d_in[16];
    const float* dtb_w     = (const float*)d_in[17];
    const float* dtb_b     = (const float*)d_in[18];
    const float* A_log_b   = (const float*)d_in[19];
    const float* D_b       = (const float*)d_in[20];
    const float* mnorm_g   = (const float*)d_in[21];
    const float* mnorm_b   = (const float*)d_in[22];
    const float* outproj_w = (const float*)d_in[23];
    const float* pnorm_g   = (const float*)d_in[24];
    const float* pnorm_b   = (const float*)d_in[25];
    const float* projback_w= (const float*)d_in[26];
    const float* projback_b= (const float*)d_in[27];
    const float* cw_w      = (const float*)d_in[28];
    const float* cw_b      = (const float*)d_in[29];
    const float* cwln_g    = (const float*)d_in[30];
    const float* cwln_b    = (const float*)d_in[31];

    float* ws = (float*)d_ws;
    float* x0n      = ws;                       // 1,048,576
    float* combined = x0n + 1048576;            // 2,097,152
    float* xz       = combined + 2097152;       // 4,194,304
    float* weight   = xz + 4194304;             // 1,048,576
    float* xdbl_f   = weight + 1048576;         //   262,144
    float* xdbl_b   = xdbl_f + 262144;          //   262,144
    float* xconv_f  = xdbl_b + 262144;          // 2,097,152
    float* xconv_b  = xconv_f + 2097152;        // 2,097,152
    float* delta_f  = xconv_b + 2097152;        // 2,097,152
    float* delta_b  = delta_f + 2097152;        // 2,097,152
    float* y_f      = delta_b + 2097152;        // 2,097,152
    float* y_b      = y_f + 2097152;            // 2,097,152
    float* chunkH_f = y_b + 2097152;            // 1,048,576  (NCHUNK=32 state)
    float* chunkH_b = chunkH_f + 1048576;       // 1,048,576  -> total ~90 MB
    // chunkA aliases combined (dead between cw GEMM and combine_mnorm):
    float* chunkA_f = combined;                 // 1,048,576
    float* chunkA_b = combined + 1048576;       // 1,048,576
    float* yn  = combined;   // written after scans complete
    float* o1  = xconv_f;    // dead after scan
    float* on1 = xconv_b;    // dead after scan

    // 1. LN of both inputs -> x0n, combined
    ln01_kernel<<<NROWS / 4, 256, 0, stream>>>(input0, input1, norm0_g, norm0_b,
                                               norm1_g, norm1_b, x0n, combined);

    // 2. xz = combined @ in_proj_w^T
    gemm_mfma_kernel<0><<<dim3(16, 64, 1), 256, 0, stream>>>(
        combined, combined, DMODEL, in_proj_w, in_proj_w, DMODEL,
        xz, xz, 2 * DINNER, DMODEL, nullptr, nullptr);

    // 3. cw_pre = combined @ cw_w^T + cw_b
    gemm_mfma_kernel<0><<<dim3(4, 64, 1), 256, 0, stream>>>(
        combined, combined, DMODEL, cw_w, cw_w, DMODEL,
        weight, weight, CH, DMODEL, cw_b, cw_b);

    // 4. weight = clip(sigmoid(LN(cw_pre)))
    weight_ln_kernel<<<NROWS / 4, 256, 0, stream>>>(weight, cwln_g, cwln_b);

    // 5. conv + silu, both directions in one pass over xz
    conv_both_kernel<<<NROWS * DINNER / 256, 256, 0, stream>>>(
        xz, convf_w, convf_b, convb_w, convb_b, xconv_f, xconv_b);

    // 6. x_dbl = xconv @ xproj_w^T  (batched f/b)
    gemm_mfma_kernel<0><<<dim3(1, 64, 2), 256, 0, stream>>>(
        xconv_f, xconv_b, DINNER, xprojf_w, xprojb_w, DINNER,
        xdbl_f, xdbl_b, 64, DINNER, nullptr, nullptr);

    // 7. delta = softplus(x_dbl[:, :32] @ dt_w^T + dt_b)  (batched f/b)
    gemm_mfma_kernel<1><<<dim3(8, 64, 2), 256, 0, stream>>>(
        xdbl_f, xdbl_b, 64, dtf_w, dtb_w, DTRANK,
        delta_f, delta_b, DINNER, DTRANK, dtf_b, dtb_b);

    // 8. chunked scan (pass1/2/3, both directions per launch)
    dim3 sgrid(DINNER / 256, NCHUNK, 2 * BDIM);
    scan_pass1_kernel<<<sgrid, 256, 0, stream>>>(
        delta_f, delta_b, xconv_f, xconv_b, xdbl_f, xdbl_b, A_log_f, A_log_b,
        chunkA_f, chunkA_b, chunkH_f, chunkH_b);
    scan_pass2_kernel<<<256, 256, 0, stream>>>(chunkA_f, chunkA_b, chunkH_f, chunkH_b);
    scan_pass3_kernel<<<sgrid, 256, 0, stream>>>(
        delta_f, delta_b, xconv_f, xconv_b, xdbl_f, xdbl_b, A_log_f, A_log_b,
        D_f, D_b, chunkH_f, chunkH_b, y_f, y_b);

    // 9. combine + mnorm LN -> yn
    combine_mnorm_kernel<<<NROWS / 4, 256, 0, stream>>>(y_f, y_b, xz, mnorm_g, mnorm_b, yn);

    // 10. o1 = yn @ outproj_w^T
    gemm_mfma_kernel<0><<<dim3(8, 64, 1), 256, 0, stream>>>(
        yn, yn, DINNER, outproj_w, outproj_w, DINNER,
        o1, o1, DMODEL, DINNER, nullptr, nullptr);

    // 11. pnorm LN -> on1
    ln512_kernel<<<NROWS / 4, 256, 0, stream>>>(o1, pnorm_g, pnorm_b, on1);

    // 12+13. projback GEMM fused with final blend + skip -> fp32 out
    gemm_projback_final_kernel<<<dim3(4, 64, 1), 256, 0, stream>>>(
        on1, DMODEL, projback_w, DMODEL, DMODEL, projback_b,
        weight, x0n, input0, (float*)d_out);
}

// Round 7
// 276.538 us; speedup vs baseline: 5.1720x; 1.1484x over previous
//
#include <hip/hip_runtime.h>

#define BDIM 4
#define SEQ 1024
#define CH 256
#define DMODEL 512
#define DINNER 512
#define DSTATE 16
#define DTRANK 32
#define NROWS (BDIM * SEQ)   // 4096
#define NCHUNK 32
#define CHUNK (SEQ / NCHUNK) // 32

typedef unsigned short ushort_t;

__device__ __forceinline__ float nan2num(float x) {
    if (isnan(x)) return 0.f;
    if (isinf(x)) return x > 0.f ? 1.f : -1.f;
    return x;
}

__device__ __forceinline__ float silu_f(float x) { return x / (1.f + __expf(-x)); }
__device__ __forceinline__ float sigmoid_f(float x) { return 1.f / (1.f + __expf(-x)); }
__device__ __forceinline__ float softplus_f(float x) {
    return x > 20.f ? x : log1pf(__expf(x));
}

// fp32 <-> bf16
__device__ __forceinline__ ushort_t f2bf(float x) {
    union { float f; unsigned u; } v; v.f = x;
    unsigned r = v.u + 0x7fff + ((v.u >> 16) & 1);
    return (ushort_t)(r >> 16);
}
__device__ __forceinline__ float bf2f(ushort_t x) {
    union { unsigned u; float f; } v; v.u = ((unsigned)x) << 16;
    return v.f;
}

using bf16x8 = __attribute__((ext_vector_type(8))) __bf16;
using f32x4  = __attribute__((ext_vector_type(4))) float;

__device__ __forceinline__ void wave_reduce2(float& s, float& q) {
#pragma unroll
    for (int m = 32; m > 0; m >>= 1) {
        s += __shfl_xor(s, m);
        q += __shfl_xor(q, m);
    }
}

// ---------------------------------------------------------------------------
// convert all GEMM weights fp32 -> bf16 (one-shot, layout: concatenated)
// ---------------------------------------------------------------------------
#define SZ_INPROJ (1024 * 512)
#define SZ_CW     (256 * 512)
#define SZ_XP     (64 * 512)
#define SZ_DT     (512 * 32)
#define SZ_OUTP   (512 * 512)
#define SZ_PROJB  (256 * 512)
#define SZ_WTOT   (SZ_INPROJ + SZ_CW + 2 * SZ_XP + 2 * SZ_DT + SZ_OUTP + SZ_PROJB)

__global__ __launch_bounds__(256) void convert_weights_kernel(
        const float* __restrict__ w0, const float* __restrict__ w1,
        const float* __restrict__ w2, const float* __restrict__ w3,
        const float* __restrict__ w4, const float* __restrict__ w5,
        const float* __restrict__ w6, const float* __restrict__ w7,
        ushort_t* __restrict__ out) {
    int i = blockIdx.x * 256 + threadIdx.x;
    if (i >= SZ_WTOT) return;
    int j = i;
    const float* src;
    if (j < SZ_INPROJ) { src = w0; }
    else { j -= SZ_INPROJ;
        if (j < SZ_CW) { src = w1; }
        else { j -= SZ_CW;
            if (j < SZ_XP) { src = w2; }
            else { j -= SZ_XP;
                if (j < SZ_XP) { src = w3; }
                else { j -= SZ_XP;
                    if (j < SZ_DT) { src = w4; }
                    else { j -= SZ_DT;
                        if (j < SZ_DT) { src = w5; }
                        else { j -= SZ_DT;
                            if (j < SZ_OUTP) { src = w6; }
                            else { j -= SZ_OUTP; src = w7; }
                        }
                    }
                }
            }
        }
    }
    out[i] = f2bf(src[j]);
}

// ---------------------------------------------------------------------------
// ln01: wave-per-row LN of i0,i1 (fp32 in) -> x0n fp32, combined bf16
// ---------------------------------------------------------------------------
__global__ __launch_bounds__(256) void ln01_kernel(
        const float* __restrict__ i0, const float* __restrict__ i1,
        const float* __restrict__ g0, const float* __restrict__ b0,
        const float* __restrict__ g1, const float* __restrict__ b1,
        float* __restrict__ x0n, ushort_t* __restrict__ combined) {
    int w = threadIdx.x >> 6, lane = threadIdx.x & 63;
    int row = blockIdx.x * 4 + w;

    float4 v = ((const float4*)(i0 + row * CH))[lane];
    v.x = nan2num(v.x); v.y = nan2num(v.y); v.z = nan2num(v.z); v.w = nan2num(v.w);
    float s = v.x + v.y + v.z + v.w;
    float q = v.x * v.x + v.y * v.y + v.z * v.z + v.w * v.w;
    wave_reduce2(s, q);
    float m = s / (float)CH;
    float r = rsqrtf(q / (float)CH - m * m + 1e-5f);
    float4 g = ((const float4*)g0)[lane];
    float4 bb = ((const float4*)b0)[lane];
    float4 o;
    o.x = (v.x - m) * r * g.x + bb.x;
    o.y = (v.y - m) * r * g.y + bb.y;
    o.z = (v.z - m) * r * g.z + bb.z;
    o.w = (v.w - m) * r * g.w + bb.w;
    ((float4*)(x0n + row * CH))[lane] = o;
    *(ushort4*)(combined + row * DMODEL + lane * 4) =
        make_ushort4(f2bf(o.x), f2bf(o.y), f2bf(o.z), f2bf(o.w));

    v = ((const float4*)(i1 + row * CH))[lane];
    v.x = nan2num(v.x); v.y = nan2num(v.y); v.z = nan2num(v.z); v.w = nan2num(v.w);
    s = v.x + v.y + v.z + v.w;
    q = v.x * v.x + v.y * v.y + v.z * v.z + v.w * v.w;
    wave_reduce2(s, q);
    m = s / (float)CH;
    r = rsqrtf(q / (float)CH - m * m + 1e-5f);
    g = ((const float4*)g1)[lane];
    bb = ((const float4*)b1)[lane];
    o.x = (v.x - m) * r * g.x + bb.x;
    o.y = (v.y - m) * r * g.y + bb.y;
    o.z = (v.z - m) * r * g.z + bb.z;
    o.w = (v.w - m) * r * g.w + bb.w;
    *(ushort4*)(combined + row * DMODEL + CH + lane * 4) =
        make_ushort4(f2bf(o.x), f2bf(o.y), f2bf(o.z), f2bf(o.w));
}

// ---------------------------------------------------------------------------
// gemm64: 64x64 tile, BK=32, bf16 A/W (HBM) -> bf16 C. Dual-batch blockIdx.z.
// ---------------------------------------------------------------------------
template<int ACT>
__global__ __launch_bounds__(256) void gemm64_kernel(
        const ushort_t* __restrict__ A0, const ushort_t* __restrict__ A1, int lda,
        const ushort_t* __restrict__ W0, const ushort_t* __restrict__ W1, int ldw,
        ushort_t* __restrict__ C0, ushort_t* __restrict__ C1, int ldc,
        int K, const float* __restrict__ bias0, const float* __restrict__ bias1) {
    const ushort_t* A = blockIdx.z ? A1 : A0;
    const ushort_t* W = blockIdx.z ? W1 : W0;
    ushort_t* C = blockIdx.z ? C1 : C0;
    const float* bias = blockIdx.z ? bias1 : bias0;

    __shared__ __align__(16) ushort_t As[64][40];
    __shared__ __align__(16) ushort_t Ws[64][40];
    const int t = threadIdx.x;
    const int m0 = blockIdx.y * 64;
    const int n0 = blockIdx.x * 64;
    const int w = t >> 6;
    const int lane = t & 63;
    const int lane16 = lane & 15;
    const int quad = lane >> 4;
    const int wr = (w >> 1) * 32;
    const int wc = (w & 1) * 32;
    const int srow = t >> 2;          // 0..63
    const int sc8 = (t & 3) * 8;      // 0,8,16,24

    f32x4 acc[2][2] = {};

    for (int k0 = 0; k0 < K; k0 += 32) {
        float4 av = *(const float4*)(A + (m0 + srow) * lda + k0 + sc8);
        float4 wv = *(const float4*)(W + (n0 + srow) * ldw + k0 + sc8);
        *(float4*)&As[srow][sc8] = av;
        *(float4*)&Ws[srow][sc8] = wv;
        __syncthreads();

        bf16x8 af[2], bfr[2];
#pragma unroll
        for (int i = 0; i < 2; ++i) {
            af[i]  = *(bf16x8*)&As[wr + i * 16 + lane16][quad * 8];
            bfr[i] = *(bf16x8*)&Ws[wc + i * 16 + lane16][quad * 8];
        }
#pragma unroll
        for (int i = 0; i < 2; ++i)
#pragma unroll
            for (int j = 0; j < 2; ++j)
                acc[i][j] = __builtin_amdgcn_mfma_f32_16x16x32_bf16(af[i], bfr[j], acc[i][j], 0, 0, 0);
        __syncthreads();
    }

#pragma unroll
    for (int j = 0; j < 2; ++j) {
        int col = n0 + wc + j * 16 + lane16;
        float bv = bias ? bias[col] : 0.f;
#pragma unroll
        for (int i = 0; i < 2; ++i) {
#pragma unroll
            for (int r = 0; r < 4; ++r) {
                int row = m0 + wr + i * 16 + quad * 4 + r;
                float c = acc[i][j][r] + bv;
                if (ACT == 1) c = softplus_f(c);
                C[row * ldc + col] = f2bf(c);
            }
        }
    }
}

// ---------------------------------------------------------------------------
// gemm128: 128x64 tile, BK=32, wave tile 64x32 (acc[4][2]). bf16 in/out.
// ---------------------------------------------------------------------------
template<int ACT>
__global__ __launch_bounds__(256) void gemm128_kernel(
        const ushort_t* __restrict__ A0, const ushort_t* __restrict__ A1, int lda,
        const ushort_t* __restrict__ W0, const ushort_t* __restrict__ W1, int ldw,
        ushort_t* __restrict__ C0, ushort_t* __restrict__ C1, int ldc,
        int K, const float* __restrict__ bias0, const float* __restrict__ bias1) {
    const ushort_t* A = blockIdx.z ? A1 : A0;
    const ushort_t* W = blockIdx.z ? W1 : W0;
    ushort_t* C = blockIdx.z ? C1 : C0;
    const float* bias = blockIdx.z ? bias1 : bias0;

    __shared__ __align__(16) ushort_t As[128][40];
    __shared__ __align__(16) ushort_t Ws[64][40];
    const int t = threadIdx.x;
    const int m0 = blockIdx.y * 128;
    const int n0 = blockIdx.x * 64;
    const int w = t >> 6;
    const int lane = t & 63;
    const int lane16 = lane & 15;
    const int quad = lane >> 4;
    const int wr = (w >> 1) * 64;   // 0 or 64
    const int wc = (w & 1) * 32;    // 0 or 32
    const int arow = t >> 1;          // 0..127
    const int ac = (t & 1) * 16;      // 0 or 16
    const int srow = t >> 2;          // 0..63
    const int sc8 = (t & 3) * 8;

    f32x4 acc[4][2] = {};

    for (int k0 = 0; k0 < K; k0 += 32) {
        float4 a0 = *(const float4*)(A + (m0 + arow) * lda + k0 + ac);
        float4 a1 = *(const float4*)(A + (m0 + arow) * lda + k0 + ac + 8);
        float4 wv = *(const float4*)(W + (n0 + srow) * ldw + k0 + sc8);
        *(float4*)&As[arow][ac] = a0;
        *(float4*)&As[arow][ac + 8] = a1;
        *(float4*)&Ws[srow][sc8] = wv;
        __syncthreads();

        bf16x8 af[4], bfr[2];
#pragma unroll
        for (int i = 0; i < 4; ++i)
            af[i] = *(bf16x8*)&As[wr + i * 16 + lane16][quad * 8];
#pragma unroll
        for (int j = 0; j < 2; ++j)
            bfr[j] = *(bf16x8*)&Ws[wc + j * 16 + lane16][quad * 8];
#pragma unroll
        for (int i = 0; i < 4; ++i)
#pragma unroll
            for (int j = 0; j < 2; ++j)
                acc[i][j] = __builtin_amdgcn_mfma_f32_16x16x32_bf16(af[i], bfr[j], acc[i][j], 0, 0, 0);
        __syncthreads();
    }

#pragma unroll
    for (int j = 0; j < 2; ++j) {
        int col = n0 + wc + j * 16 + lane16;
        float bv = bias ? bias[col] : 0.f;
#pragma unroll
        for (int i = 0; i < 4; ++i) {
#pragma unroll
            for (int r = 0; r < 4; ++r) {
                int row = m0 + wr + i * 16 + quad * 4 + r;
                float c = acc[i][j][r] + bv;
                if (ACT == 1) c = softplus_f(c);
                C[row * ldc + col] = f2bf(c);
            }
        }
    }
}

// ---------------------------------------------------------------------------
// projback GEMM + final blend fused (A,W,wgt bf16; x0n,i0,out fp32)
// ---------------------------------------------------------------------------
__global__ __launch_bounds__(256) void gemm_projback_final_kernel(
        const ushort_t* __restrict__ A, int lda,
        const ushort_t* __restrict__ W, int ldw,
        int K, const float* __restrict__ bias,
        const ushort_t* __restrict__ wgt, const float* __restrict__ x0n,
        const float* __restrict__ i0, float* __restrict__ out) {
    __shared__ __align__(16) ushort_t As[64][40];
    __shared__ __align__(16) ushort_t Ws[64][40];
    const int t = threadIdx.x;
    const int m0 = blockIdx.y * 64;
    const int n0 = blockIdx.x * 64;
    const int w = t >> 6;
    const int lane = t & 63;
    const int lane16 = lane & 15;
    const int quad = lane >> 4;
    const int wr = (w >> 1) * 32;
    const int wc = (w & 1) * 32;
    const int srow = t >> 2;
    const int sc8 = (t & 3) * 8;

    f32x4 acc[2][2] = {};

    for (int k0 = 0; k0 < K; k0 += 32) {
        float4 av = *(const float4*)(A + (m0 + srow) * lda + k0 + sc8);
        float4 wv = *(const float4*)(W + (n0 + srow) * ldw + k0 + sc8);
        *(float4*)&As[srow][sc8] = av;
        *(float4*)&Ws[srow][sc8] = wv;
        __syncthreads();

        bf16x8 af[2], bfr[2];
#pragma unroll
        for (int i = 0; i < 2; ++i) {
            af[i]  = *(bf16x8*)&As[wr + i * 16 + lane16][quad * 8];
            bfr[i] = *(bf16x8*)&Ws[wc + i * 16 + lane16][quad * 8];
        }
#pragma unroll
        for (int i = 0; i < 2; ++i)
#pragma unroll
            for (int j = 0; j < 2; ++j)
                acc[i][j] = __builtin_amdgcn_mfma_f32_16x16x32_bf16(af[i], bfr[j], acc[i][j], 0, 0, 0);
        __syncthreads();
    }

#pragma unroll
    for (int j = 0; j < 2; ++j) {
        int col = n0 + wc + j * 16 + lane16;
        float bv = bias[col];
#pragma unroll
        for (int i = 0; i < 2; ++i) {
#pragma unroll
            for (int r = 0; r < 4; ++r) {
                int row = m0 + wr + i * 16 + quad * 4 + r;
                float o = nan2num(acc[i][j][r] + bv);
                float wv = bf2f(wgt[row * CH + col]);
                float xv = x0n[row * CH + col];
                float sk = nan2num(i0[row * CH + col]);
                out[row * CH + col] = o * wv + xv * (1.f - wv) + sk;
            }
        }
    }
}

// ---------------------------------------------------------------------------
// weight = clip(sigmoid(LN(cw_pre)), .01, .99) in place (bf16), wave-per-row
// ---------------------------------------------------------------------------
__global__ __launch_bounds__(256) void weight_ln_kernel(
        ushort_t* __restrict__ wbuf, const float* __restrict__ g, const float* __restrict__ b) {
    int w = threadIdx.x >> 6, lane = threadIdx.x & 63;
    int row = blockIdx.x * 4 + w;
    ushort4 raw = *(const ushort4*)(wbuf + row * CH + lane * 4);
    float4 v = make_float4(bf2f(raw.x), bf2f(raw.y), bf2f(raw.z), bf2f(raw.w));
    float s = v.x + v.y + v.z + v.w;
    float q = v.x * v.x + v.y * v.y + v.z * v.z + v.w * v.w;
    wave_reduce2(s, q);
    float m = s / (float)CH;
    float r = rsqrtf(q / (float)CH - m * m + 1e-5f);
    float4 g4 = ((const float4*)g)[lane];
    float4 b4 = ((const float4*)b)[lane];
    float ox = fminf(fmaxf(sigmoid_f((v.x - m) * r * g4.x + b4.x), 0.01f), 0.99f);
    float oy = fminf(fmaxf(sigmoid_f((v.y - m) * r * g4.y + b4.y), 0.01f), 0.99f);
    float oz = fminf(fmaxf(sigmoid_f((v.z - m) * r * g4.z + b4.z), 0.01f), 0.99f);
    float ow = fminf(fmaxf(sigmoid_f((v.w - m) * r * g4.w + b4.w), 0.01f), 0.99f);
    *(ushort4*)(wbuf + row * CH + lane * 4) = make_ushort4(f2bf(ox), f2bf(oy), f2bf(oz), f2bf(ow));
}

// ---------------------------------------------------------------------------
// depthwise causal conv (w=4) + bias + silu, both dirs. bf16 in/out.
// ---------------------------------------------------------------------------
__global__ __launch_bounds__(256) void conv_both_kernel(
        const ushort_t* __restrict__ xz,
        const float* __restrict__ wf, const float* __restrict__ wbf,
        const float* __restrict__ wb, const float* __restrict__ wbb,
        ushort_t* __restrict__ outf, ushort_t* __restrict__ outb) {
    int flat = blockIdx.x * 256 + threadIdx.x;   // over 4096*512
    int d = flat & (DINNER - 1);
    int row = flat >> 9;
    int l = row & (SEQ - 1);
    int b = row >> 10;
    float accf = wbf[d], accb = wbb[d];
#pragma unroll
    for (int k = 0; k < 4; ++k) {
        int jf = l - 3 + k;
        if (jf >= 0) accf += bf2f(xz[(b * SEQ + jf) * (2 * DINNER) + d]) * wf[d * 4 + k];
        int jb = l + 3 - k;
        if (jb < SEQ) accb += bf2f(xz[(b * SEQ + jb) * (2 * DINNER) + d]) * wb[d * 4 + k];
    }
    outf[flat] = f2bf(silu_f(accf));
    outb[(b * SEQ + (SEQ - 1 - l)) * DINNER + d] = f2bf(silu_f(accb));
}

// ---------------------------------------------------------------------------
// Scan pass 1 (thread-per-d): bf16 delta/u/xdbl, fp32 chunk state out.
// ---------------------------------------------------------------------------
__global__ __launch_bounds__(256) void scan_pass1_kernel(
        const ushort_t* __restrict__ df, const ushort_t* __restrict__ db,
        const ushort_t* __restrict__ uf, const ushort_t* __restrict__ ub,
        const ushort_t* __restrict__ xf, const ushort_t* __restrict__ xb,
        const float* __restrict__ Alf, const float* __restrict__ Alb,
        float* __restrict__ cAf, float* __restrict__ cAb,
        float* __restrict__ cHf, float* __restrict__ cHb) {
    const int dir = blockIdx.z >> 2;
    const int b = blockIdx.z & 3;
    const ushort_t* delta = dir ? db : df;
    const ushort_t* u     = dir ? ub : uf;
    const ushort_t* xdbl  = dir ? xb : xf;
    const float* A_log    = dir ? Alb : Alf;
    float* chunkA = dir ? cAb : cAf;
    float* chunkH = dir ? cHb : cHf;

    const int c = blockIdx.y;
    const int d = blockIdx.x * 256 + threadIdx.x;
    const int base = b * SEQ + c * CHUNK;

    __shared__ float sB[CHUNK][16];
    {
        int t = threadIdx.x;
        if (t < CHUNK * 2) {                 // 64 threads x 8 bf16
            int row = t >> 1, f8 = (t & 1) * 8;
            float4 raw = *(const float4*)(xdbl + (base + row) * 64 + DTRANK + f8);
            const ushort_t* us = (const ushort_t*)&raw;
#pragma unroll
            for (int k = 0; k < 8; ++k) sB[row][f8 + k] = bf2f(us[k]);
        }
    }
    __syncthreads();

    float a[DSTATE];
#pragma unroll
    for (int n = 0; n < DSTATE; n += 4) {
        float4 al = *(const float4*)(A_log + d * DSTATE + n);
        a[n] = -__expf(al.x); a[n + 1] = -__expf(al.y);
        a[n + 2] = -__expf(al.z); a[n + 3] = -__expf(al.w);
    }
    float h[DSTATE];
#pragma unroll
    for (int n = 0; n < DSTATE; ++n) h[n] = 0.f;

    float sumdl = 0.f;
    float dl = bf2f(delta[base * DINNER + d]);
    float ul = bf2f(u[base * DINNER + d]);
    for (int s = 0; s < CHUNK; ++s) {
        int nrow = base + ((s + 1 < CHUNK) ? s + 1 : s);
        float dln = bf2f(delta[nrow * DINNER + d]);
        float uln = bf2f(u[nrow * DINNER + d]);
        float dlul = dl * ul;
        sumdl += dl;
#pragma unroll
        for (int g = 0; g < 4; ++g) {
            float4 B4 = *(const float4*)&sB[s][g * 4];
            float dA0 = __expf(dl * a[g * 4 + 0]);
            float dA1 = __expf(dl * a[g * 4 + 1]);
            float dA2 = __expf(dl * a[g * 4 + 2]);
            float dA3 = __expf(dl * a[g * 4 + 3]);
            h[g * 4 + 0] = dA0 * h[g * 4 + 0] + dlul * B4.x;
            h[g * 4 + 1] = dA1 * h[g * 4 + 1] + dlul * B4.y;
            h[g * 4 + 2] = dA2 * h[g * 4 + 2] + dlul * B4.z;
            h[g * 4 + 3] = dA3 * h[g * 4 + 3] + dlul * B4.w;
        }
        dl = dln; ul = uln;
    }

    int idx = ((b * NCHUNK + c) * DINNER + d) * DSTATE;
#pragma unroll
    for (int n = 0; n < DSTATE; n += 4) {
        float4 P4 = make_float4(__expf(a[n] * sumdl), __expf(a[n + 1] * sumdl),
                                __expf(a[n + 2] * sumdl), __expf(a[n + 3] * sumdl));
        *(float4*)(chunkA + idx + n) = P4;
        *(float4*)(chunkH + idx + n) = make_float4(h[n], h[n + 1], h[n + 2], h[n + 3]);
    }
}

// ---------------------------------------------------------------------------
// Pass 2: sequential combine over chunks (fp32, in place)
// ---------------------------------------------------------------------------
__global__ __launch_bounds__(256) void scan_pass2_kernel(
        const float* __restrict__ cAf, const float* __restrict__ cAb,
        float* __restrict__ cHf, float* __restrict__ cHb) {
    int tid = blockIdx.x * 256 + threadIdx.x;   // 0..65535
    int dir = tid >> 15;
    int rr = tid & 32767;
    int b = rr >> 13;
    int rem = rr & 8191;
    const float* chunkA = dir ? cAb : cAf;
    float* chunkH = dir ? cHb : cHf;
    float h = 0.f;
    for (int c = 0; c < NCHUNK; ++c) {
        int idx = (b * NCHUNK + c) * (DINNER * DSTATE) + rem;
        float Ac = chunkA[idx];
        float Hc = chunkH[idx];
        chunkH[idx] = h;
        h = Ac * h + Hc;
    }
}

// ---------------------------------------------------------------------------
// Pass 3 (thread-per-d): re-scan seeded, emit y (bf16).
// ---------------------------------------------------------------------------
__global__ __launch_bounds__(256) void scan_pass3_kernel(
        const ushort_t* __restrict__ df, const ushort_t* __restrict__ db,
        const ushort_t* __restrict__ uf, const ushort_t* __restrict__ ub,
        const ushort_t* __restrict__ xf, const ushort_t* __restrict__ xb,
        const float* __restrict__ Alf, const float* __restrict__ Alb,
        const float* __restrict__ Dvf, const float* __restrict__ Dvb,
        const float* __restrict__ hfb, const float* __restrict__ hbb,
        ushort_t* __restrict__ yfo, ushort_t* __restrict__ ybo) {
    const int dir = blockIdx.z >> 2;
    const int b = blockIdx.z & 3;
    const ushort_t* delta = dir ? db : df;
    const ushort_t* u     = dir ? ub : uf;
    const ushort_t* xdbl  = dir ? xb : xf;
    const float* A_log    = dir ? Alb : Alf;
    const float* Dv       = dir ? Dvb : Dvf;
    const float* hin      = dir ? hbb : hfb;
    ushort_t* yout        = dir ? ybo : yfo;

    const int c = blockIdx.y;
    const int d = blockIdx.x * 256 + threadIdx.x;
    const int base = b * SEQ + c * CHUNK;

    __shared__ float sBC[CHUNK][32];
    {
        int t = threadIdx.x;
        if (t < CHUNK * 4) {                 // 128 threads x 8 bf16
            int row = t >> 2, f8 = (t & 3) * 8;
            float4 raw = *(const float4*)(xdbl + (base + row) * 64 + DTRANK + f8);
            const ushort_t* us = (const ushort_t*)&raw;
#pragma unroll
            for (int k = 0; k < 8; ++k) sBC[row][f8 + k] = bf2f(us[k]);
        }
    }
    __syncthreads();

    float a[DSTATE];
#pragma unroll
    for (int n = 0; n < DSTATE; n += 4) {
        float4 al = *(const float4*)(A_log + d * DSTATE + n);
        a[n] = -__expf(al.x); a[n + 1] = -__expf(al.y);
        a[n + 2] = -__expf(al.z); a[n + 3] = -__expf(al.w);
    }
    float h[DSTATE];
    {
        int idx = ((b * NCHUNK + c) * DINNER + d) * DSTATE;
#pragma unroll
        for (int n = 0; n < DSTATE; n += 4) {
            float4 h4 = *(const float4*)(hin + idx + n);
            h[n] = h4.x; h[n + 1] = h4.y; h[n + 2] = h4.z; h[n + 3] = h4.w;
        }
    }
    const float Dd = Dv[d];

    float dl = bf2f(delta[base * DINNER + d]);
    float ul = bf2f(u[base * DINNER + d]);
    for (int s = 0; s < CHUNK; ++s) {
        int nrow = base + ((s + 1 < CHUNK) ? s + 1 : s);
        float dln = bf2f(delta[nrow * DINNER + d]);
        float uln = bf2f(u[nrow * DINNER + d]);
        float dlul = dl * ul;
        float y = 0.f;
#pragma unroll
        for (int g = 0; g < 4; ++g) {
            float4 B4 = *(const float4*)&sBC[s][g * 4];
            float4 C4 = *(const float4*)&sBC[s][16 + g * 4];
            float dA0 = __expf(dl * a[g * 4 + 0]);
            float dA1 = __expf(dl * a[g * 4 + 1]);
            float dA2 = __expf(dl * a[g * 4 + 2]);
            float dA3 = __expf(dl * a[g * 4 + 3]);
            h[g * 4 + 0] = dA0 * h[g * 4 + 0] + dlul * B4.x;
            h[g * 4 + 1] = dA1 * h[g * 4 + 1] + dlul * B4.y;
            h[g * 4 + 2] = dA2 * h[g * 4 + 2] + dlul * B4.z;
            h[g * 4 + 3] = dA3 * h[g * 4 + 3] + dlul * B4.w;
            y += h[g * 4 + 0] * C4.x + h[g * 4 + 1] * C4.y
               + h[g * 4 + 2] * C4.z + h[g * 4 + 3] * C4.w;
        }
        int lpos = c * CHUNK + s;
        int orow = b * SEQ + (dir ? (SEQ - 1 - lpos) : lpos);
        yout[orow * DINNER + d] = f2bf(y + Dd * ul);
        dl = dln; ul = uln;
    }
}

// ---------------------------------------------------------------------------
// combine + mnorm, wave-per-row; 8 bf16 per lane. bf16 in/out.
// ---------------------------------------------------------------------------
__global__ __launch_bounds__(256) void combine_mnorm_kernel(
        const ushort_t* __restrict__ yf, const ushort_t* __restrict__ yb,
        const ushort_t* __restrict__ xz,
        const float* __restrict__ g, const float* __restrict__ b,
        ushort_t* __restrict__ yn) {
    int w = threadIdx.x >> 6, lane = threadIdx.x & 63;
    int row = blockIdx.x * 4 + w;
    float4 rf = *(const float4*)(yf + row * DINNER + lane * 8);
    float4 rb = *(const float4*)(yb + row * DINNER + lane * 8);
    float4 rz = *(const float4*)(xz + row * (2 * DINNER) + DINNER + lane * 8);
    const ushort_t* uf = (const ushort_t*)&rf;
    const ushort_t* ub = (const ushort_t*)&rb;
    const ushort_t* uz = (const ushort_t*)&rz;
    float v[8];
    float s = 0.f, q = 0.f;
#pragma unroll
    for (int k = 0; k < 8; ++k) {
        float val = 0.5f * (bf2f(uf[k]) + bf2f(ub[k])) * silu_f(bf2f(uz[k]));
        v[k] = val; s += val; q += val * val;
    }
    wave_reduce2(s, q);
    float m = s / (float)DINNER;
    float r = rsqrtf(q / (float)DINNER - m * m + 1e-5f);
    ushort_t o[8];
#pragma unroll
    for (int k = 0; k < 8; ++k)
        o[k] = f2bf((v[k] - m) * r * g[lane * 8 + k] + b[lane * 8 + k]);
    *(ushort4*)(yn + row * DINNER + lane * 8) = make_ushort4(o[0], o[1], o[2], o[3]);
    *(ushort4*)(yn + row * DINNER + lane * 8 + 4) = make_ushort4(o[4], o[5], o[6], o[7]);
}

// ---------------------------------------------------------------------------
// pnorm LN over 512, wave-per-row, bf16 in/out
// ---------------------------------------------------------------------------
__global__ __launch_bounds__(256) void ln512_kernel(
        const ushort_t* __restrict__ in,
        const float* __restrict__ g, const float* __restrict__ b,
        ushort_t* __restrict__ out) {
    int w = threadIdx.x >> 6, lane = threadIdx.x & 63;
    int row = blockIdx.x * 4 + w;
    float4 raw = *(const float4*)(in + row * DMODEL + lane * 8);
    const ushort_t* us = (const ushort_t*)&raw;
    float v[8];
    float s = 0.f, q = 0.f;
#pragma unroll
    for (int k = 0; k < 8; ++k) {
        v[k] = bf2f(us[k]); s += v[k]; q += v[k] * v[k];
    }
    wave_reduce2(s, q);
    float m = s / (float)DMODEL;
    float r = rsqrtf(q / (float)DMODEL - m * m + 1e-5f);
    ushort_t o[8];
#pragma unroll
    for (int k = 0; k < 8; ++k)
        o[k] = f2bf((v[k] - m) * r * g[lane * 8 + k] + b[lane * 8 + k]);
    *(ushort4*)(out + row * DMODEL + lane * 8) = make_ushort4(o[0], o[1], o[2], o[3]);
    *(ushort4*)(out + row * DMODEL + lane * 8 + 4) = make_ushort4(o[4], o[5], o[6], o[7]);
}

extern "C" void kernel_launch(void* const* d_in, const int* in_sizes, int n_in,
                              void* d_out, int out_size, void* d_ws, size_t ws_size,
                              hipStream_t stream) {
    (void)in_sizes; (void)n_in; (void)out_size; (void)ws_size;
    const float* input0    = (const float*)d_in[0];
    const float* input1    = (const float*)d_in[1];
    const float* norm0_g   = (const float*)d_in[2];
    const float* norm0_b   = (const float*)d_in[3];
    const float* norm1_g   = (const float*)d_in[4];
    const float* norm1_b   = (const float*)d_in[5];
    const float* in_proj_w = (const float*)d_in[6];
    const float* convf_w   = (const float*)d_in[7];
    const float* convf_b   = (const float*)d_in[8];
    const float* xprojf_w  = (const float*)d_in[9];
    const float* dtf_w     = (const float*)d_in[10];
    const float* dtf_b     = (const float*)d_in[11];
    const float* A_log_f   = (const float*)d_in[12];
    const float* D_f       = (const float*)d_in[13];
    const float* convb_w   = (const float*)d_in[14];
    const float* convb_b   = (const float*)d_in[15];
    const float* xprojb_w  = (const float*)d_in[16];
    const float* dtb_w     = (const float*)d_in[17];
    const float* dtb_b     = (const float*)d_in[18];
    const float* A_log_b   = (const float*)d_in[19];
    const float* D_b       = (const float*)d_in[20];
    const float* mnorm_g   = (const float*)d_in[21];
    const float* mnorm_b   = (const float*)d_in[22];
    const float* outproj_w = (const float*)d_in[23];
    const float* pnorm_g   = (const float*)d_in[24];
    const float* pnorm_b   = (const float*)d_in[25];
    const float* projback_w= (const float*)d_in[26];
    const float* projback_b= (const float*)d_in[27];
    const float* cw_w      = (const float*)d_in[28];
    const float* cw_b      = (const float*)d_in[29];
    const float* cwln_g    = (const float*)d_in[30];
    const float* cwln_b    = (const float*)d_in[31];

    // ---- workspace layout ----
    // fp32 region first
    float* wsf = (float*)d_ws;
    float* x0n      = wsf;                      // 1,048,576 f
    float* chunkA_f = x0n + 1048576;            // 1,048,576 f
    float* chunkA_b = chunkA_f + 1048576;       // 1,048,576 f
    float* chunkH_f = chunkA_b + 1048576;       // 1,048,576 f
    float* chunkH_b = chunkH_f + 1048576;       // 1,048,576 f
    // bf16 region (ushort)
    ushort_t* wsu = (ushort_t*)(chunkH_b + 1048576);
    ushort_t* combined = wsu;                   // 2,097,152 u
    ushort_t* xz       = combined + 2097152;    // 4,194,304 u
    ushort_t* weight   = xz + 4194304;          // 1,048,576 u
    ushort_t* xdbl_f   = weight + 1048576;      //   262,144 u
    ushort_t* xdbl_b   = xdbl_f + 262144;       //   262,144 u
    ushort_t* xconv_f  = xdbl_b + 262144;       // 2,097,152 u
    ushort_t* xconv_b  = xconv_f + 2097152;     // 2,097,152 u
    ushort_t* delta_f  = xconv_b + 2097152;     // 2,097,152 u
    ushort_t* delta_b  = delta_f + 2097152;     // 2,097,152 u
    ushort_t* y_f      = delta_b + 2097152;     // 2,097,152 u
    ushort_t* y_b      = y_f + 2097152;         // 2,097,152 u
    ushort_t* yn       = y_b + 2097152;         // 2,097,152 u
    ushort_t* o1       = yn + 2097152;          // 2,097,152 u
    ushort_t* on1      = o1 + 2097152;          // 2,097,152 u
    // bf16 weights
    ushort_t* wb       = on1 + 2097152;
    ushort_t* w_inproj = wb;
    ushort_t* w_cw     = w_inproj + SZ_INPROJ;
    ushort_t* w_xpf    = w_cw + SZ_CW;
    ushort_t* w_xpb    = w_xpf + SZ_XP;
    ushort_t* w_dtf    = w_xpb + SZ_XP;
    ushort_t* w_dtb    = w_dtf + SZ_DT;
    ushort_t* w_outp   = w_dtb + SZ_DT;
    ushort_t* w_projb  = w_outp + SZ_OUTP;
    // total ~76 MB

    // 0. convert weights to bf16
    convert_weights_kernel<<<(SZ_WTOT + 255) / 256, 256, 0, stream>>>(
        in_proj_w, cw_w, xprojf_w, xprojb_w, dtf_w, dtb_w, outproj_w, projback_w, wb);

    // 1. LN of both inputs -> x0n (fp32), combined (bf16)
    ln01_kernel<<<NROWS / 4, 256, 0, stream>>>(input0, input1, norm0_g, norm0_b,
                                               norm1_g, norm1_b, x0n, combined);

    // 2. xz = combined @ in_proj_w^T   (128-tile)
    gemm128_kernel<0><<<dim3(16, 32, 1), 256, 0, stream>>>(
        combined, combined, DMODEL, w_inproj, w_inproj, DMODEL,
        xz, xz, 2 * DINNER, DMODEL, nullptr, nullptr);

    // 3. cw_pre = combined @ cw_w^T + cw_b   (64-tile)
    gemm64_kernel<0><<<dim3(4, 64, 1), 256, 0, stream>>>(
        combined, combined, DMODEL, w_cw, w_cw, DMODEL,
        weight, weight, CH, DMODEL, cw_b, cw_b);

    // 4. weight = clip(sigmoid(LN(cw_pre)))
    weight_ln_kernel<<<NROWS / 4, 256, 0, stream>>>(weight, cwln_g, cwln_b);

    // 5. conv + silu, both directions
    conv_both_kernel<<<NROWS * DINNER / 256, 256, 0, stream>>>(
        xz, convf_w, convf_b, convb_w, convb_b, xconv_f, xconv_b);

    // 6. x_dbl = xconv @ xproj_w^T  (64-tile, batched f/b)
    gemm64_kernel<0><<<dim3(1, 64, 2), 256, 0, stream>>>(
        xconv_f, xconv_b, DINNER, w_xpf, w_xpb, DINNER,
        xdbl_f, xdbl_b, 64, DINNER, nullptr, nullptr);

    // 7. delta = softplus(x_dbl[:, :32] @ dt_w^T + dt_b)  (128-tile, batched)
    gemm128_kernel<1><<<dim3(8, 32, 2), 256, 0, stream>>>(
        xdbl_f, xdbl_b, 64, w_dtf, w_dtb, DTRANK,
        delta_f, delta_b, DINNER, DTRANK, dtf_b, dtb_b);

    // 8. chunked scan
    dim3 sgrid(DINNER / 256, NCHUNK, 2 * BDIM);
    scan_pass1_kernel<<<sgrid, 256, 0, stream>>>(
        delta_f, delta_b, xconv_f, xconv_b, xdbl_f, xdbl_b, A_log_f, A_log_b,
        chunkA_f, chunkA_b, chunkH_f, chunkH_b);
    scan_pass2_kernel<<<256, 256, 0, stream>>>(chunkA_f, chunkA_b, chunkH_f, chunkH_b);
    scan_pass3_kernel<<<sgrid, 256, 0, stream>>>(
        delta_f, delta_b, xconv_f, xconv_b, xdbl_f, xdbl_b, A_log_f, A_log_b,
        D_f, D_b, chunkH_f, chunkH_b, y_f, y_b);

    // 9. combine + mnorm LN -> yn
    combine_mnorm_kernel<<<NROWS / 4, 256, 0, stream>>>(y_f, y_b, xz, mnorm_g, mnorm_b, yn);

    // 10. o1 = yn @ outproj_w^T  (128-tile)
    gemm128_kernel<0><<<dim3(8, 32, 1), 256, 0, stream>>>(
        yn, yn, DINNER, w_outp, w_outp, DINNER,
        o1, o1, DMODEL, DINNER, nullptr, nullptr);

    // 11. pnorm LN -> on1
    ln512_kernel<<<NROWS / 4, 256, 0, stream>>>(o1, pnorm_g, pnorm_b, on1);

    // 12+13. projback GEMM fused with final blend + skip -> fp32 out
    gemm_projback_final_kernel<<<dim3(4, 64, 1), 256, 0, stream>>>(
        on1, DMODEL, w_projb, DMODEL, DMODEL, projback_b,
        weight, x0n, input0, (float*)d_out);
}